// Round 13
// baseline (308.804 us; speedup 1.0000x reference)
//
#include <hip/hip_runtime.h>
#include <math.h>

#define DEV static __device__ __forceinline__

typedef unsigned int  u32;
typedef unsigned short u16;

using bf16x8 = __attribute__((ext_vector_type(8))) __bf16;
using f32x4  = __attribute__((ext_vector_type(4))) float;

static constexpr int B_ = 16;
static constexpr int C_ = 512;
static constexpr int H_ = 48;
static constexpr int W_ = 48;
static constexpr int L_ = 2304;      // H*W
static constexpr int M_ = B_ * L_;   // 36864
static constexpr int SEG_ = 48;      // scan segments (2304 = 48*48)
static constexpr int TSEG_ = 48;
static constexpr int NLB_ = 144;     // ln_in blocks per batch (L/16)

DEV float silu_(float v) { return v / (1.f + __expf(-v)); }
DEV float bflo(u32 p) { return __uint_as_float(p << 16); }
DEV float bfhi(u32 p) { return __uint_as_float(p & 0xffff0000u); }
DEV float bf2f(u16 v) { return __uint_as_float(((u32)v) << 16); }
DEV u16 f2bf(float f) { u32 u = __float_as_uint(f); u32 r = u + 0x7fffu + ((u >> 16) & 1u); return (u16)(r >> 16); }

// direction k, segment s (TSEG=48): sp = sp0 + step*i, i in [0,48)
DEV void seg_affine(int k, int s, int& sp0, int& step) {
  if (k == 0)      { sp0 = 48 * s;        step = 1;   }
  else if (k == 1) { sp0 = 2303 - 48 * s; step = -1;  }
  else if (k == 2) { sp0 = s;             step = 48;  }
  else             { sp0 = 2303 - s;      step = -48; }
}

// ================= MFMA GEMM helpers (tiles with T2 XOR swizzle) =================
DEV void stage_tile(u16* Ls, const u16* __restrict__ g, int ld) {
  const int tid = threadIdx.x;
  #pragma unroll
  for (int i = 0; i < 4; ++i) {
    int c = i * 256 + tid;
    int row = c >> 3, slot = c & 7;
    uint4 v = *(const uint4*)(g + (size_t)row * ld + slot * 8);
    int b = row * 128 + ((slot * 16) ^ ((row & 7) << 4));
    *(uint4*)((char*)Ls + b) = v;
  }
}

DEV void stage_tile32(u16* Ls, const u16* __restrict__ g, int ld) {
  const int c = threadIdx.x;          // 32 rows x 8 slots = 256 chunks
  int row = c >> 3, slot = c & 7;
  uint4 v = *(const uint4*)(g + (size_t)row * ld + slot * 8);
  int b = row * 128 + ((slot * 16) ^ ((row & 7) << 4));
  *(uint4*)((char*)Ls + b) = v;
}

DEV bf16x8 lds_frag(const u16* Ls, int row, int kbyte) {
  int b = row * 128 + (kbyte ^ ((row & 7) << 4));
  return *(const bf16x8*)((const char*)Ls + b);
}

// ---------------- K0: weight prep: transpose + bf16 convert ----------------
__global__ __launch_bounds__(256) void k_prep(const float* __restrict__ Win,
    const float* __restrict__ Wout, const float* __restrict__ projw,
    u16* __restrict__ WinT, u16* __restrict__ WoutT, u16* __restrict__ projwT) {
  int id = blockIdx.x * 256 + threadIdx.x;
  if (id < 131072) {
    int k = id >> 15, rem = id & 32767;
    int r = rem >> 8, n = rem & 255;
    WinT[(k << 15) + n * 128 + r] = f2bf(Win[id]);
  } else if (id < 196608) {
    int t = id - 131072;
    int k = t >> 14, rem = t & 16383;
    int r = rem >> 7, n = rem & 127;
    WoutT[(k << 14) + n * 128 + r] = f2bf(Wout[t]);
  } else {
    int t = id - 196608;
    int r = t >> 9, n = t & 511;
    projwT[n * 512 + r] = f2bf(projw[t]);
  }
}

// ---------------- K1: layernorm over C of x (B,L,C) + fused SE column partials ----------------
__global__ __launch_bounds__(256) void k_ln_in(const float* __restrict__ x,
    const float* __restrict__ w, const float* __restrict__ bia, u16* __restrict__ xs,
    float* __restrict__ zpart) {
  __shared__ float tile[16 * 513];
  __shared__ float smean[16], srstd[16];
  const int b = blockIdx.y;
  const int l0 = blockIdx.x * 16;
  const int tid = threadIdx.x;
  const float* xb = x + (size_t)b * C_ * L_;
  for (int idx = tid; idx < C_ * 16; idx += 256) {
    int c = idx >> 4, lt = idx & 15;
    tile[lt * 513 + c] = xb[(size_t)c * L_ + l0 + lt];
  }
  __syncthreads();
  {
    const int j = tid & 15, g = tid >> 4;
    float s1 = 0.f, s2 = 0.f;
    #pragma unroll
    for (int i = 0; i < 32; ++i) {
      float v = tile[g * 513 + j + i * 16];
      s1 += v; s2 += v * v;
    }
    #pragma unroll
    for (int o = 8; o; o >>= 1) { s1 += __shfl_xor(s1, o, 16); s2 += __shfl_xor(s2, o, 16); }
    if (j == 0) {
      float mean = s1 * (1.f / C_);
      float var = s2 * (1.f / C_) - mean * mean;
      smean[g] = mean;
      srstd[g] = rsqrtf(var + 1e-5f);
    }
  }
  __syncthreads();
  float p0 = 0.f, p1 = 0.f;
  for (int idx = tid; idx < 16 * C_; idx += 256) {
    int lt = idx >> 9, c = idx & 511;
    float v = (tile[lt * 513 + c] - smean[lt]) * srstd[lt] * w[c] + bia[c];
    xs[((size_t)b * L_ + l0 + lt) * C_ + c] = f2bf(v);
    if (c == tid) p0 += v; else p1 += v;
  }
  float* zp = zpart + ((size_t)b * NLB_ + blockIdx.x) * 512;
  zp[tid] = p0;
  zp[tid + 256] = p1;
}

// ---------------- K2: finish SE column means ----------------
__global__ __launch_bounds__(256) void k_colsum_fin(const float* __restrict__ zpart, float* __restrict__ z) {
  const int c = blockIdx.x * 256 + threadIdx.x;
  const int b = blockIdx.y;
  float acc = 0.f;
  for (int s = 0; s < NLB_; ++s) acc += zpart[((size_t)b * NLB_ + s) * 512 + c];
  z[b * C_ + c] = acc * (1.f / L_);
}

// ---------------- K3: SE MLP ----------------
__global__ __launch_bounds__(256) void k_se(const float* __restrict__ z,
    const float* __restrict__ fc1w, const float* __restrict__ fc1b,
    const float* __restrict__ fc2w, const float* __restrict__ fc2b, float* __restrict__ se) {
  __shared__ float zs[512];
  __shared__ float hs[32];
  const int b = blockIdx.x, tid = threadIdx.x;
  zs[tid] = z[b * C_ + tid];
  zs[tid + 256] = z[b * C_ + tid + 256];
  __syncthreads();
  if (tid < 32) {
    float a = fc1b[tid];
    for (int c = 0; c < 512; ++c) a += zs[c] * fc1w[c * 32 + tid];
    hs[tid] = fmaxf(a, 0.f);
  }
  __syncthreads();
  for (int c = tid; c < 512; c += 256) {
    float a = fc2b[c];
    #pragma unroll
    for (int r = 0; r < 32; ++r) a += hs[r] * fc2w[r * 512 + c];
    se[b * C_ + c] = 1.f / (1.f + __expf(-a));
  }
}

// ---------------- K4: xz GEMM (MFMA), XCD-chunk swizzled 1D grid ----------------
__global__ __launch_bounds__(256) void k_gemm_xz(const u16* __restrict__ xs,
    const u16* __restrict__ WinT, u16* __restrict__ xin, u16* __restrict__ zbuf) {
  __shared__ u16 lds[16384];
  u16* As = lds; u16* Bs = lds + 8192;
  const int hw = blockIdx.x;                         // 2304 blocks
  const int lg = (hw & 7) * 288 + (hw >> 3);         // same-A pairs -> same XCD
  const int nb = lg & 1;
  const int m0 = ((lg >> 1) % 288) * 128;
  const int k = lg / 576;
  const int tid = threadIdx.x, l = tid & 63, w = tid >> 6;
  const int wm = w >> 1, wn = w & 1;
  const int fr = l & 15, fg = l >> 4;
  f32x4 acc[4][4];
  #pragma unroll
  for (int mi = 0; mi < 4; ++mi)
    #pragma unroll
    for (int ni = 0; ni < 4; ++ni) acc[mi][ni] = (f32x4){0.f, 0.f, 0.f, 0.f};
  const u16* Ag = xs + (size_t)m0 * 512 + k * 128;
  const u16* Bg = WinT + (size_t)k * 32768 + (size_t)nb * 16384;
  #pragma unroll
  for (int kk0 = 0; kk0 < 128; kk0 += 64) {
    stage_tile(As, Ag + kk0, 512);
    stage_tile(Bs, Bg + kk0, 128);
    __syncthreads();
    bf16x8 af[2][4], bfr[2][4];
    #pragma unroll
    for (int h = 0; h < 2; ++h)
      #pragma unroll
      for (int s = 0; s < 4; ++s) {
        af[h][s]  = lds_frag(As, wm * 64 + s * 16 + fr, h * 64 + fg * 16);
        bfr[h][s] = lds_frag(Bs, wn * 64 + s * 16 + fr, h * 64 + fg * 16);
      }
    #pragma unroll
    for (int h = 0; h < 2; ++h)
      #pragma unroll
      for (int mi = 0; mi < 4; ++mi)
        #pragma unroll
        for (int ni = 0; ni < 4; ++ni)
          acc[mi][ni] = __builtin_amdgcn_mfma_f32_16x16x32_bf16(af[h][mi], bfr[h][ni], acc[mi][ni], 0, 0, 0);
    __syncthreads();
  }
  #pragma unroll
  for (int mi = 0; mi < 4; ++mi)
    #pragma unroll
    for (int ni = 0; ni < 4; ++ni)
      #pragma unroll
      for (int j = 0; j < 4; ++j)
        lds[(wm * 64 + mi * 16 + fg * 4 + j) * 128 + wn * 64 + ni * 16 + fr] = f2bf(acc[mi][ni][j]);
  __syncthreads();
  u16* dst = (nb == 0 ? xin : zbuf) + ((size_t)k * M_ + m0) * 128;
  for (int idx = tid; idx < 128 * 16; idx += 256) {
    int row = idx >> 4, q = idx & 15;
    *(uint4*)&dst[(size_t)row * 128 + q * 8] = *(const uint4*)&lds[row * 128 + q * 8];
  }
}

// ---------------- K5: fused depthwise 3x3 conv + bias + silu + x_dbl ----------------
// R7 structure; taps/wxs use 12-word group stride: base 48g bytes is 16B-aligned
// (float4 reads kept) and bank-quads 12g mod 32 give exactly 2 lanes/bank (free).
__global__ __launch_bounds__(256) void k_dwconv(const u16* __restrict__ xin,
    const float* __restrict__ cw, const float* __restrict__ cb, const float* __restrict__ Wx,
    u16* __restrict__ xc, float* __restrict__ xdbl) {
  __shared__ float taps[9 * 192];      // t*192 + g*12 + j
  __shared__ float wxs[10 * 192];      // r*192 + g*12 + j
  __shared__ float part[16][16][10];   // [sl][g][r]
  const int kb = blockIdx.y;
  const int k = kb >> 4;
  const int tid = threadIdx.x;
  for (int i = tid; i < 1152; i += 256) {
    int dc = i / 9, t = i - dc * 9;
    taps[t * 192 + (dc >> 3) * 12 + (dc & 7)] = cw[((size_t)k * 128 + dc) * 9 + t];
  }
  for (int i = tid; i < 1280; i += 256) {
    int r = i >> 7, dc = i & 127;
    wxs[r * 192 + (dc >> 3) * 12 + (dc & 7)] = Wx[(size_t)k * 1280 + i];
  }
  __syncthreads();
  const int sl = tid >> 4, g = tid & 15;
  const int sp = blockIdx.x * 16 + sl;
  const int h = sp / W_, w = sp % W_;
  const int dc0 = g * 8;
  const int tb = g * 12;
  float acc[8];
  {
    float4 b0 = *(const float4*)(cb + k * 128 + dc0);
    float4 b1 = *(const float4*)(cb + k * 128 + dc0 + 4);
    acc[0] = b0.x; acc[1] = b0.y; acc[2] = b0.z; acc[3] = b0.w;
    acc[4] = b1.x; acc[5] = b1.y; acc[6] = b1.z; acc[7] = b1.w;
  }
  const u16* base = xin + (size_t)kb * L_ * 128 + dc0;
  #pragma unroll
  for (int dy = -1; dy <= 1; ++dy) {
    int hh = h + dy;
    if (hh < 0 || hh >= H_) continue;
    #pragma unroll
    for (int dx = -1; dx <= 1; ++dx) {
      int ww = w + dx;
      if (ww < 0 || ww >= W_) continue;
      uint4 v = *(const uint4*)(base + (size_t)(hh * W_ + ww) * 128);
      const float* tp = &taps[((dy + 1) * 3 + dx + 1) * 192 + tb];
      acc[0] += tp[0] * bflo(v.x);
      acc[1] += tp[1] * bfhi(v.x);
      acc[2] += tp[2] * bflo(v.y);
      acc[3] += tp[3] * bfhi(v.y);
      acc[4] += tp[4] * bflo(v.z);
      acc[5] += tp[5] * bfhi(v.z);
      acc[6] += tp[6] * bflo(v.w);
      acc[7] += tp[7] * bfhi(v.w);
    }
  }
  float u[8];
  u16 ov[8];
  #pragma unroll
  for (int j = 0; j < 8; ++j) { u[j] = silu_(acc[j]); ov[j] = f2bf(u[j]); }
  *(uint4*)(xc + ((size_t)kb * L_ + sp) * 128 + dc0) = *(const uint4*)ov;
  #pragma unroll
  for (int r = 0; r < 10; ++r) {
    const float* wr = &wxs[r * 192 + tb];
    float pv = 0.f;
    #pragma unroll
    for (int j = 0; j < 8; ++j) pv += wr[j] * u[j];
    part[sl][g][r] = pv;
  }
  __syncthreads();
  if (tid < 160) {
    int sl2 = tid / 10, r = tid - sl2 * 10;
    float s = 0.f;
    #pragma unroll
    for (int g2 = 0; g2 < 16; ++g2) s += part[sl2][g2][r];
    xdbl[((size_t)kb * L_ + blockIdx.x * 16 + sl2) * 16 + r] = s;
  }
}

// ---------------- K6: delta = softplus(dtb + Wdt . dt_row), bf16 ----------------
__global__ __launch_bounds__(256) void k_delta(const float* __restrict__ xdbl,
    const float* __restrict__ Wdt, const float* __restrict__ dtb, u16* __restrict__ delt) {
  __shared__ float xrow[16][8];
  const int kb = blockIdx.y;
  const int k = kb >> 4;
  const int tid = threadIdx.x;
  const int sp0 = blockIdx.x * 16;
  if (tid < 128) {
    int sl = tid >> 3, r = tid & 7;
    xrow[sl][r] = xdbl[((size_t)kb * L_ + sp0 + sl) * 16 + r];
  }
  const int dc = tid & 127, shalf = tid >> 7;
  const float4 w0 = *(const float4*)(Wdt + (size_t)k * 1024 + dc * 8);
  const float4 w1 = *(const float4*)(Wdt + (size_t)k * 1024 + dc * 8 + 4);
  const float db = dtb[k * 128 + dc];
  __syncthreads();
  u16* dst = delt + ((size_t)kb * L_ + sp0 + shalf * 8) * 128 + dc;
  #pragma unroll
  for (int i = 0; i < 8; ++i) {
    const float* r = xrow[shalf * 8 + i];
    float dt = db + w0.x * r[0] + w0.y * r[1] + w0.z * r[2] + w0.w * r[3]
                  + w1.x * r[4] + w1.y * r[5] + w1.z * r[6] + w1.w * r[7];
    float delta = (dt > 20.f) ? dt : __logf(1.f + __expf(dt));
    dst[(size_t)i * 128] = f2bf(delta);
  }
}

// ---------------- K7: scan pass A: segment aggregates (light) ----------------
__global__ __launch_bounds__(256) void k_scan_passA(const u16* __restrict__ xc,
    const u16* __restrict__ delt, const float* __restrict__ xdbl,
    const float* __restrict__ Alog, float* __restrict__ segA, float* __restrict__ segB) {
  const int kb = blockIdx.y;
  const int k = kb >> 4;
  const int s = blockIdx.x * 2 + (threadIdx.x >> 7);
  const int dc = threadIdx.x & 127;
  const float Aa = -__expf(Alog[k * 128 + dc]);
  int sp0, step;
  seg_affine(k, s, sp0, step);
  const u16* up = xc + ((size_t)kb * L_ + sp0) * 128 + dc;
  const u16* dp = delt + ((size_t)kb * L_ + sp0) * 128 + dc;
  const float* xr = xdbl + ((size_t)kb * L_ + sp0) * 16 + 8;
  const int ustep = step * 128, xstep = step * 16;
  float a = 1.f, bacc = 0.f;
  #pragma unroll 4
  for (int i = 0; i < TSEG_; ++i) {
    float Bm = *xr;
    float u = bf2f(*up);
    float delta = bf2f(*dp);
    float dA = __expf(delta * Aa);
    a *= dA;
    bacc = dA * bacc + delta * u * Bm;
    up += ustep; dp += ustep; xr += xstep;
  }
  segA[((size_t)kb * SEG_ + s) * 128 + dc] = a;
  segB[((size_t)kb * SEG_ + s) * 128 + dc] = bacc;
}

// ---------------- K8: scan pass B ----------------
__global__ __launch_bounds__(128) void k_scan_passB(const float* __restrict__ segA,
    const float* __restrict__ segB, float* __restrict__ hpre) {
  const int kb = blockIdx.x;
  const int dc = threadIdx.x;
  float h = 0.f;
  for (int s = 0; s < SEG_; ++s) {
    size_t o = ((size_t)kb * SEG_ + s) * 128 + dc;
    hpre[o] = h;
    h = segA[o] * h + segB[o];
  }
}

// ---------------- K9: scan pass C: apply + fused onorm-LN + silu gate (wave-local) ----------------
__global__ __launch_bounds__(256) void k_scan_passC(u16* __restrict__ xc,
    const u16* __restrict__ delt, const float* __restrict__ xdbl, const u16* __restrict__ zbuf,
    const float* __restrict__ Alog, const float* __restrict__ Dp, const float* __restrict__ hpre,
    const float* __restrict__ ow, const float* __restrict__ ob) {
  const int unit = blockIdx.x * 4 + (threadIdx.x >> 6);   // (kb, s) pair per wave
  const int kb = unit / SEG_;
  const int s = unit - kb * SEG_;
  const int k = kb >> 4;
  const int lane = threadIdx.x & 63;
  const float Aa0 = -__expf(Alog[k * 128 + lane]);
  const float Aa1 = -__expf(Alog[k * 128 + lane + 64]);
  const float Dv0 = Dp[k * 128 + lane],      Dv1 = Dp[k * 128 + lane + 64];
  const float lw0 = ow[k * 128 + lane],      lw1 = ow[k * 128 + lane + 64];
  const float lb0 = ob[k * 128 + lane],      lb1 = ob[k * 128 + lane + 64];
  int sp0, step;
  seg_affine(k, s, sp0, step);
  size_t base = ((size_t)kb * L_ + sp0) * 128 + lane;
  u16* up = xc + base;
  const u16* dp = delt + base;
  const u16* zp = zbuf + base;
  const float* xr = xdbl + ((size_t)kb * L_ + sp0) * 16 + 8;
  const int ustep = step * 128, xstep = step * 16;
  float h0 = hpre[((size_t)kb * SEG_ + s) * 128 + lane];
  float h1 = hpre[((size_t)kb * SEG_ + s) * 128 + lane + 64];
  for (int i = 0; i < TSEG_; ++i) {
    float Bm = xr[0], Cm = xr[1];
    float u0 = bf2f(up[0]), u1 = bf2f(up[64]);
    float d0 = bf2f(dp[0]), d1 = bf2f(dp[64]);
    float z0 = bf2f(zp[0]), z1 = bf2f(zp[64]);
    float dA0 = __expf(d0 * Aa0), dA1 = __expf(d1 * Aa1);
    h0 = dA0 * h0 + d0 * u0 * Bm;
    h1 = dA1 * h1 + d1 * u1 * Bm;
    float y0 = h0 * Cm + Dv0 * u0;
    float y1 = h1 * Cm + Dv1 * u1;
    float s1 = y0 + y1, s2 = y0 * y0 + y1 * y1;
    #pragma unroll
    for (int o = 32; o; o >>= 1) { s1 += __shfl_xor(s1, o, 64); s2 += __shfl_xor(s2, o, 64); }
    float mean = s1 * (1.f / 128.f);
    float rstd = rsqrtf(s2 * (1.f / 128.f) - mean * mean + 1e-5f);
    up[0]  = f2bf(((y0 - mean) * rstd * lw0 + lb0) * silu_(z0));
    up[64] = f2bf(((y1 - mean) * rstd * lw1 + lb1) * silu_(z1));
    up += ustep; dp += ustep; zp += ustep; xr += xstep;
  }
}

// ---------------- K11: fused Wout GEMM (all 4 k) + skip*xh*se + row-LN(512) ----------------
__global__ __launch_bounds__(256) void k_wout_ln(const u16* __restrict__ t,
    const u16* __restrict__ WoutT, const u16* __restrict__ xs, const float* __restrict__ se,
    const float* __restrict__ skip, const float* __restrict__ nw, const float* __restrict__ nb,
    u16* __restrict__ xln) {
  __shared__ u16 As[2048];            // 32 x 64 (swizzled rows of 128B)
  __shared__ u16 Bs[8192];            // 128 x 64
  __shared__ u16 stage[32 * 520];     // 32 rows x 512 cols, stride 520
  const int m0 = blockIdx.x * 32;
  const int tid = threadIdx.x, l = tid & 63, w = tid >> 6;
  const int wm = w >> 1, wn = w & 1;
  const int fr = l & 15, fg = l >> 4;
  for (int k = 0; k < 4; ++k) {
    f32x4 acc[4];
    #pragma unroll
    for (int ni = 0; ni < 4; ++ni) acc[ni] = (f32x4){0.f, 0.f, 0.f, 0.f};
    const u16* Ag = t + ((size_t)k * M_ + m0) * 128;
    const u16* Bg = WoutT + (size_t)k * 16384;
    #pragma unroll
    for (int kk0 = 0; kk0 < 128; kk0 += 64) {
      stage_tile32(As, Ag + kk0, 128);
      stage_tile(Bs, Bg + kk0, 128);
      __syncthreads();
      bf16x8 af[2], bfr[2][4];
      #pragma unroll
      for (int h = 0; h < 2; ++h) {
        af[h] = lds_frag(As, wm * 16 + fr, h * 64 + fg * 16);
        #pragma unroll
        for (int s = 0; s < 4; ++s)
          bfr[h][s] = lds_frag(Bs, wn * 64 + s * 16 + fr, h * 64 + fg * 16);
      }
      #pragma unroll
      for (int h = 0; h < 2; ++h)
        #pragma unroll
        for (int ni = 0; ni < 4; ++ni)
          acc[ni] = __builtin_amdgcn_mfma_f32_16x16x32_bf16(af[h], bfr[h][ni], acc[ni], 0, 0, 0);
      __syncthreads();
    }
    #pragma unroll
    for (int ni = 0; ni < 4; ++ni)
      #pragma unroll
      for (int j = 0; j < 4; ++j)
        stage[(wm * 16 + fg * 4 + j) * 520 + k * 128 + wn * 64 + ni * 16 + fr] = f2bf(acc[ni][j]);
  }
  __syncthreads();
  const int row = tid >> 3, t7 = tid & 7;
  const int m = m0 + row;
  const int b = m / L_;
  const float sk = skip[0];
  float s1 = 0.f, s2 = 0.f;
  #pragma unroll
  for (int i = 0; i < 8; ++i) {
    int col = t7 * 8 + i * 64;
    uint4 cv = *(const uint4*)&stage[row * 520 + col];
    uint4 xv = *(const uint4*)&xs[(size_t)m * 512 + col];
    float4 e0 = *(const float4*)&se[b * 512 + col];
    float4 e1 = *(const float4*)&se[b * 512 + col + 4];
    float o[8];
    o[0] = bflo(cv.x) * sk * bflo(xv.x) * e0.x;
    o[1] = bfhi(cv.x) * sk * bfhi(xv.x) * e0.y;
    o[2] = bflo(cv.y) * sk * bflo(xv.y) * e0.z;
    o[3] = bfhi(cv.y) * sk * bfhi(xv.y) * e0.w;
    o[4] = bflo(cv.z) * sk * bflo(xv.z) * e1.x;
    o[5] = bfhi(cv.z) * sk * bfhi(xv.z) * e1.y;
    o[6] = bflo(cv.w) * sk * bflo(xv.w) * e1.z;
    o[7] = bfhi(cv.w) * sk * bfhi(xv.w) * e1.w;
    u16 ov[8];
    #pragma unroll
    for (int j = 0; j < 8; ++j) { s1 += o[j]; s2 += o[j] * o[j]; ov[j] = f2bf(o[j]); }
    *(uint4*)&stage[row * 520 + col] = *(const uint4*)ov;
  }
  #pragma unroll
  for (int o = 4; o; o >>= 1) { s1 += __shfl_xor(s1, o, 64); s2 += __shfl_xor(s2, o, 64); }
  float mean = s1 * (1.f / C_);
  float rstd = rsqrtf(s2 * (1.f / C_) - mean * mean + 1e-5f);
  #pragma unroll
  for (int i = 0; i < 8; ++i) {
    int col = t7 * 8 + i * 64;
    uint4 cv = *(const uint4*)&stage[row * 520 + col];
    float4 w0 = *(const float4*)&nw[col];
    float4 w1 = *(const float4*)&nw[col + 4];
    float4 b0 = *(const float4*)&nb[col];
    float4 b1 = *(const float4*)&nb[col + 4];
    u16 ov[8];
    ov[0] = f2bf((bflo(cv.x) - mean) * rstd * w0.x + b0.x);
    ov[1] = f2bf((bfhi(cv.x) - mean) * rstd * w0.y + b0.y);
    ov[2] = f2bf((bflo(cv.y) - mean) * rstd * w0.z + b0.z);
    ov[3] = f2bf((bfhi(cv.y) - mean) * rstd * w0.w + b0.w);
    ov[4] = f2bf((bflo(cv.z) - mean) * rstd * w1.x + b1.x);
    ov[5] = f2bf((bfhi(cv.z) - mean) * rstd * w1.y + b1.y);
    ov[6] = f2bf((bflo(cv.w) - mean) * rstd * w1.z + b1.z);
    ov[7] = f2bf((bfhi(cv.w) - mean) * rstd * w1.w + b1.w);
    *(uint4*)&xln[(size_t)m * 512 + col] = *(const uint4*)ov;
  }
}

// ---------------- K13: proj GEMM (MFMA) + bias, XCD-chunk swizzled, transposed write ----------------
__global__ __launch_bounds__(256) void k_gemm_proj(const u16* __restrict__ xln,
    const u16* __restrict__ projwT, const float* __restrict__ projb, float* __restrict__ outp) {
  __shared__ float ldsp[8448];
  u16* As = (u16*)ldsp; u16* Bs = As + 8192;
  const int hw = blockIdx.x;                    // 1152 blocks
  const int lg = (hw & 7) * 144 + (hw >> 3);    // same-A quads -> same XCD
  const int n0 = (lg & 3) * 128;
  const int m0 = (lg >> 2) * 128;
  const int tid = threadIdx.x, l = tid & 63, w = tid >> 6;
  const int wm = w >> 1, wn = w & 1;
  const int fr = l & 15, fg = l >> 4;
  f32x4 acc[4][4];
  #pragma unroll
  for (int mi = 0; mi < 4; ++mi)
    #pragma unroll
    for (int ni = 0; ni < 4; ++ni) acc[mi][ni] = (f32x4){0.f, 0.f, 0.f, 0.f};
  const u16* Ag = xln + (size_t)m0 * 512;
  const u16* Bg = projwT + (size_t)n0 * 512;
  for (int kk0 = 0; kk0 < 512; kk0 += 64) {
    stage_tile(As, Ag + kk0, 512);
    stage_tile(Bs, Bg + kk0, 512);
    __syncthreads();
    bf16x8 af[2][4], bfr[2][4];
    #pragma unroll
    for (int h = 0; h < 2; ++h)
      #pragma unroll
      for (int s = 0; s < 4; ++s) {
        af[h][s]  = lds_frag(As, wm * 64 + s * 16 + fr, h * 64 + fg * 16);
        bfr[h][s] = lds_frag(Bs, wn * 64 + s * 16 + fr, h * 64 + fg * 16);
      }
    #pragma unroll
    for (int h = 0; h < 2; ++h)
      #pragma unroll
      for (int mi = 0; mi < 4; ++mi)
        #pragma unroll
        for (int ni = 0; ni < 4; ++ni)
          acc[mi][ni] = __builtin_amdgcn_mfma_f32_16x16x32_bf16(af[h][mi], bfr[h][ni], acc[mi][ni], 0, 0, 0);
    __syncthreads();
  }
  const int b = m0 / L_, sp0 = m0 % L_;
  #pragma unroll
  for (int half = 0; half < 2; ++half) {
    if (wn == half) {
      #pragma unroll
      for (int ni = 0; ni < 4; ++ni) {
        int nl = ni * 16 + fr;
        float bias = projb[n0 + half * 64 + nl];
        #pragma unroll
        for (int mi = 0; mi < 4; ++mi)
          #pragma unroll
          for (int j = 0; j < 4; ++j)
            ldsp[nl * 132 + wm * 64 + mi * 16 + fg * 4 + j] = acc[mi][ni][j] + bias;
      }
    }
    __syncthreads();
    for (int idx = tid; idx < 64 * 32; idx += 256) {
      int n = idx >> 5, mq = idx & 31;
      float4 v = *(const float4*)&ldsp[n * 132 + mq * 4];
      *(float4*)&outp[((size_t)b * 512 + n0 + half * 64 + n) * L_ + sp0 + mq * 4] = v;
    }
    __syncthreads();
  }
}

extern "C" void kernel_launch(void* const* d_in, const int* in_sizes, int n_in,
                              void* d_out, int out_size, void* d_ws, size_t ws_size,
                              hipStream_t stream) {
  const float* x     = (const float*)d_in[0];
  const float* nw    = (const float*)d_in[1];
  const float* nb    = (const float*)d_in[2];
  const float* fc1w  = (const float*)d_in[3];
  const float* fc1b  = (const float*)d_in[4];
  const float* fc2w  = (const float*)d_in[5];
  const float* fc2b  = (const float*)d_in[6];
  const float* Win   = (const float*)d_in[7];
  const float* convw = (const float*)d_in[8];
  const float* convb = (const float*)d_in[9];
  const float* Wx    = (const float*)d_in[10];
  const float* Wdt   = (const float*)d_in[11];
  const float* dtb   = (const float*)d_in[12];
  const float* Alog  = (const float*)d_in[13];
  const float* Dp    = (const float*)d_in[14];
  const float* onw   = (const float*)d_in[15];
  const float* onb   = (const float*)d_in[16];
  const float* Wout  = (const float*)d_in[17];
  const float* projw = (const float*)d_in[18];
  const float* projb = (const float*)d_in[19];
  const float* skip  = (const float*)d_in[20];
  float* outp = (float*)d_out;

  const size_t BIGE = (size_t)4 * B_ * L_ * 128;   // 18,874,368 elements
  char* p = (char*)d_ws;
  auto carve = [&](size_t bytes) { char* r = p; p += (bytes + 255) & ~(size_t)255; return r; };
  u16*   xs     = (u16*)  carve(BIGE * 2);          // (B,L,C) bf16
  u16*   big1   = (u16*)  carve(BIGE * 2);          // xin -> delta -> xln
  u16*   big2   = (u16*)  carve(BIGE * 2);          // zbuf
  u16*   big3   = (u16*)  carve(BIGE * 2);          // xc -> t (in place)
  float* xdbl   = (float*)carve((size_t)2359296 * 4);
  float* segA   = (float*)carve((size_t)393216 * 4);
  float* segB   = (float*)carve((size_t)393216 * 4);
  float* hpre   = (float*)carve((size_t)393216 * 4);
  float* zpart  = (float*)carve((size_t)B_ * NLB_ * 512 * 4);   // 4.7 MB
  float* z      = (float*)carve((size_t)8192 * 4);
  float* se     = (float*)carve((size_t)8192 * 4);
  u16*   WinT   = (u16*)  carve((size_t)131072 * 2);
  u16*   WoutT  = (u16*)  carve((size_t)65536 * 2);
  u16*   projwT = (u16*)  carve((size_t)262144 * 2);

  k_prep<<<1792, 256, 0, stream>>>(Win, Wout, projw, WinT, WoutT, projwT);
  k_ln_in<<<dim3(NLB_, B_), 256, 0, stream>>>(x, nw, nb, xs, zpart);
  k_colsum_fin<<<dim3(2, B_), 256, 0, stream>>>(zpart, z);
  k_se<<<B_, 256, 0, stream>>>(z, fc1w, fc1b, fc2w, fc2b, se);
  k_gemm_xz<<<2304, 256, 0, stream>>>(xs, WinT, big1, big2);
  k_dwconv<<<dim3(L_ / 16, 64), 256, 0, stream>>>(big1, convw, convb, Wx, big3, xdbl);
  k_delta<<<dim3(L_ / 16, 64), 256, 0, stream>>>(xdbl, Wdt, dtb, big1);
  k_scan_passA<<<dim3(SEG_ / 2, 64), 256, 0, stream>>>(big3, big1, xdbl, Alog, segA, segB);
  k_scan_passB<<<64, 128, 0, stream>>>(segA, segB, hpre);
  k_scan_passC<<<SEG_ * 64 / 4, 256, 0, stream>>>(big3, big1, xdbl, big2, Alog, Dp, hpre, onw, onb);
  k_wout_ln<<<M_ / 32, 256, 0, stream>>>(big3, WoutT, xs, se, skip, nw, nb, big1);
  k_gemm_proj<<<1152, 256, 0, stream>>>(big1, projwT, projb, outp);
}

// Round 14
// 304.726 us; speedup vs baseline: 1.0134x; 1.0134x over previous
//
#include <hip/hip_runtime.h>
#include <math.h>

#define DEV static __device__ __forceinline__

typedef unsigned int  u32;
typedef unsigned short u16;

using bf16x8 = __attribute__((ext_vector_type(8))) __bf16;
using f32x4  = __attribute__((ext_vector_type(4))) float;

static constexpr int B_ = 16;
static constexpr int C_ = 512;
static constexpr int H_ = 48;
static constexpr int W_ = 48;
static constexpr int L_ = 2304;      // H*W
static constexpr int M_ = B_ * L_;   // 36864
static constexpr int SEG_ = 48;      // scan segments (2304 = 48*48)
static constexpr int TSEG_ = 48;
static constexpr int NLB_ = 144;     // ln_in blocks per batch (L/16)

DEV float silu_(float v) { return v / (1.f + __expf(-v)); }
DEV float bflo(u32 p) { return __uint_as_float(p << 16); }
DEV float bfhi(u32 p) { return __uint_as_float(p & 0xffff0000u); }
DEV float bf2f(u16 v) { return __uint_as_float(((u32)v) << 16); }
DEV u16 f2bf(float f) { u32 u = __float_as_uint(f); u32 r = u + 0x7fffu + ((u >> 16) & 1u); return (u16)(r >> 16); }

// direction k, segment s (TSEG=48): sp = sp0 + step*i, i in [0,48)
DEV void seg_affine(int k, int s, int& sp0, int& step) {
  if (k == 0)      { sp0 = 48 * s;        step = 1;   }
  else if (k == 1) { sp0 = 2303 - 48 * s; step = -1;  }
  else if (k == 2) { sp0 = s;             step = 48;  }
  else             { sp0 = 2303 - s;      step = -48; }
}

// ================= MFMA GEMM helpers (tiles with T2 XOR swizzle) =================
DEV void stage_tile(u16* Ls, const u16* __restrict__ g, int ld) {
  const int tid = threadIdx.x;
  #pragma unroll
  for (int i = 0; i < 4; ++i) {
    int c = i * 256 + tid;
    int row = c >> 3, slot = c & 7;
    uint4 v = *(const uint4*)(g + (size_t)row * ld + slot * 8);
    int b = row * 128 + ((slot * 16) ^ ((row & 7) << 4));
    *(uint4*)((char*)Ls + b) = v;
  }
}

DEV void stage_tile32(u16* Ls, const u16* __restrict__ g, int ld) {
  const int c = threadIdx.x;          // 32 rows x 8 slots = 256 chunks
  int row = c >> 3, slot = c & 7;
  uint4 v = *(const uint4*)(g + (size_t)row * ld + slot * 8);
  int b = row * 128 + ((slot * 16) ^ ((row & 7) << 4));
  *(uint4*)((char*)Ls + b) = v;
}

DEV bf16x8 lds_frag(const u16* Ls, int row, int kbyte) {
  int b = row * 128 + (kbyte ^ ((row & 7) << 4));
  return *(const bf16x8*)((const char*)Ls + b);
}

// ---------------- K0: weight prep: transpose + bf16 convert ----------------
__global__ __launch_bounds__(256) void k_prep(const float* __restrict__ Win,
    const float* __restrict__ Wout, const float* __restrict__ projw,
    u16* __restrict__ WinT, u16* __restrict__ WoutT, u16* __restrict__ projwT) {
  int id = blockIdx.x * 256 + threadIdx.x;
  if (id < 131072) {
    int k = id >> 15, rem = id & 32767;
    int r = rem >> 8, n = rem & 255;
    WinT[(k << 15) + n * 128 + r] = f2bf(Win[id]);
  } else if (id < 196608) {
    int t = id - 131072;
    int k = t >> 14, rem = t & 16383;
    int r = rem >> 7, n = rem & 127;
    WoutT[(k << 14) + n * 128 + r] = f2bf(Wout[t]);
  } else {
    int t = id - 196608;
    int r = t >> 9, n = t & 511;
    projwT[n * 512 + r] = f2bf(projw[t]);
  }
}

// ---------------- K1: layernorm over C of x (B,L,C) + fused SE column partials ----------------
// global loads vectorized: 8 x float4 per thread (16B/lane)
__global__ __launch_bounds__(256) void k_ln_in(const float* __restrict__ x,
    const float* __restrict__ w, const float* __restrict__ bia, u16* __restrict__ xs,
    float* __restrict__ zpart) {
  __shared__ float tile[16 * 513];
  __shared__ float smean[16], srstd[16];
  const int b = blockIdx.y;
  const int l0 = blockIdx.x * 16;
  const int tid = threadIdx.x;
  const float* xb = x + (size_t)b * C_ * L_;
  #pragma unroll
  for (int i = 0; i < 8; ++i) {
    int idx4 = i * 256 + tid;
    int c = idx4 >> 2, lt4 = (idx4 & 3) * 4;
    float4 v = *(const float4*)(xb + (size_t)c * L_ + l0 + lt4);
    tile[(lt4 + 0) * 513 + c] = v.x;
    tile[(lt4 + 1) * 513 + c] = v.y;
    tile[(lt4 + 2) * 513 + c] = v.z;
    tile[(lt4 + 3) * 513 + c] = v.w;
  }
  __syncthreads();
  {
    const int j = tid & 15, g = tid >> 4;
    float s1 = 0.f, s2 = 0.f;
    #pragma unroll
    for (int i = 0; i < 32; ++i) {
      float v = tile[g * 513 + j + i * 16];
      s1 += v; s2 += v * v;
    }
    #pragma unroll
    for (int o = 8; o; o >>= 1) { s1 += __shfl_xor(s1, o, 16); s2 += __shfl_xor(s2, o, 16); }
    if (j == 0) {
      float mean = s1 * (1.f / C_);
      float var = s2 * (1.f / C_) - mean * mean;
      smean[g] = mean;
      srstd[g] = rsqrtf(var + 1e-5f);
    }
  }
  __syncthreads();
  float p0 = 0.f, p1 = 0.f;
  for (int idx = tid; idx < 16 * C_; idx += 256) {
    int lt = idx >> 9, c = idx & 511;
    float v = (tile[lt * 513 + c] - smean[lt]) * srstd[lt] * w[c] + bia[c];
    xs[((size_t)b * L_ + l0 + lt) * C_ + c] = f2bf(v);
    if (c == tid) p0 += v; else p1 += v;
  }
  float* zp = zpart + ((size_t)b * NLB_ + blockIdx.x) * 512;
  zp[tid] = p0;
  zp[tid + 256] = p1;
}

// ---------------- K2: finish SE column means ----------------
__global__ __launch_bounds__(256) void k_colsum_fin(const float* __restrict__ zpart, float* __restrict__ z) {
  const int c = blockIdx.x * 256 + threadIdx.x;
  const int b = blockIdx.y;
  float acc = 0.f;
  for (int s = 0; s < NLB_; ++s) acc += zpart[((size_t)b * NLB_ + s) * 512 + c];
  z[b * C_ + c] = acc * (1.f / L_);
}

// ---------------- K3: SE MLP ----------------
__global__ __launch_bounds__(256) void k_se(const float* __restrict__ z,
    const float* __restrict__ fc1w, const float* __restrict__ fc1b,
    const float* __restrict__ fc2w, const float* __restrict__ fc2b, float* __restrict__ se) {
  __shared__ float zs[512];
  __shared__ float hs[32];
  const int b = blockIdx.x, tid = threadIdx.x;
  zs[tid] = z[b * C_ + tid];
  zs[tid + 256] = z[b * C_ + tid + 256];
  __syncthreads();
  if (tid < 32) {
    float a = fc1b[tid];
    for (int c = 0; c < 512; ++c) a += zs[c] * fc1w[c * 32 + tid];
    hs[tid] = fmaxf(a, 0.f);
  }
  __syncthreads();
  for (int c = tid; c < 512; c += 256) {
    float a = fc2b[c];
    #pragma unroll
    for (int r = 0; r < 32; ++r) a += hs[r] * fc2w[r * 512 + c];
    se[b * C_ + c] = 1.f / (1.f + __expf(-a));
  }
}

// ---------------- K4: xz GEMM (MFMA), XCD-chunk swizzled 1D grid ----------------
__global__ __launch_bounds__(256) void k_gemm_xz(const u16* __restrict__ xs,
    const u16* __restrict__ WinT, u16* __restrict__ xin, u16* __restrict__ zbuf) {
  __shared__ u16 lds[16384];
  u16* As = lds; u16* Bs = lds + 8192;
  const int hw = blockIdx.x;                         // 2304 blocks
  const int lg = (hw & 7) * 288 + (hw >> 3);         // same-A pairs -> same XCD
  const int nb = lg & 1;
  const int m0 = ((lg >> 1) % 288) * 128;
  const int k = lg / 576;
  const int tid = threadIdx.x, l = tid & 63, w = tid >> 6;
  const int wm = w >> 1, wn = w & 1;
  const int fr = l & 15, fg = l >> 4;
  f32x4 acc[4][4];
  #pragma unroll
  for (int mi = 0; mi < 4; ++mi)
    #pragma unroll
    for (int ni = 0; ni < 4; ++ni) acc[mi][ni] = (f32x4){0.f, 0.f, 0.f, 0.f};
  const u16* Ag = xs + (size_t)m0 * 512 + k * 128;
  const u16* Bg = WinT + (size_t)k * 32768 + (size_t)nb * 16384;
  #pragma unroll
  for (int kk0 = 0; kk0 < 128; kk0 += 64) {
    stage_tile(As, Ag + kk0, 512);
    stage_tile(Bs, Bg + kk0, 128);
    __syncthreads();
    bf16x8 af[2][4], bfr[2][4];
    #pragma unroll
    for (int h = 0; h < 2; ++h)
      #pragma unroll
      for (int s = 0; s < 4; ++s) {
        af[h][s]  = lds_frag(As, wm * 64 + s * 16 + fr, h * 64 + fg * 16);
        bfr[h][s] = lds_frag(Bs, wn * 64 + s * 16 + fr, h * 64 + fg * 16);
      }
    #pragma unroll
    for (int h = 0; h < 2; ++h)
      #pragma unroll
      for (int mi = 0; mi < 4; ++mi)
        #pragma unroll
        for (int ni = 0; ni < 4; ++ni)
          acc[mi][ni] = __builtin_amdgcn_mfma_f32_16x16x32_bf16(af[h][mi], bfr[h][ni], acc[mi][ni], 0, 0, 0);
    __syncthreads();
  }
  #pragma unroll
  for (int mi = 0; mi < 4; ++mi)
    #pragma unroll
    for (int ni = 0; ni < 4; ++ni)
      #pragma unroll
      for (int j = 0; j < 4; ++j)
        lds[(wm * 64 + mi * 16 + fg * 4 + j) * 128 + wn * 64 + ni * 16 + fr] = f2bf(acc[mi][ni][j]);
  __syncthreads();
  u16* dst = (nb == 0 ? xin : zbuf) + ((size_t)k * M_ + m0) * 128;
  for (int idx = tid; idx < 128 * 16; idx += 256) {
    int row = idx >> 4, q = idx & 15;
    *(uint4*)&dst[(size_t)row * 128 + q * 8] = *(const uint4*)&lds[row * 128 + q * 8];
  }
}

// ---------------- K5: fused depthwise 3x3 conv + bias + silu + x_dbl (R12/R7 best variant) ----------------
__global__ __launch_bounds__(256) void k_dwconv(const u16* __restrict__ xin,
    const float* __restrict__ cw, const float* __restrict__ cb, const float* __restrict__ Wx,
    u16* __restrict__ xc, float* __restrict__ xdbl) {
  __shared__ float taps[9][128];
  __shared__ float wxs[10][128];
  __shared__ float part[16][16][10];   // [sl][g][r]
  const int kb = blockIdx.y;
  const int k = kb >> 4;
  const int tid = threadIdx.x;
  for (int i = tid; i < 1152; i += 256) {
    int dc = i / 9, t = i - dc * 9;
    taps[t][dc] = cw[((size_t)k * 128 + dc) * 9 + t];
  }
  for (int i = tid; i < 1280; i += 256) wxs[i >> 7][i & 127] = Wx[(size_t)k * 1280 + i];
  __syncthreads();
  const int sl = tid >> 4, g = tid & 15;
  const int sp = blockIdx.x * 16 + sl;
  const int h = sp / W_, w = sp % W_;
  const int dc0 = g * 8;
  float acc[8];
  {
    float4 b0 = *(const float4*)(cb + k * 128 + dc0);
    float4 b1 = *(const float4*)(cb + k * 128 + dc0 + 4);
    acc[0] = b0.x; acc[1] = b0.y; acc[2] = b0.z; acc[3] = b0.w;
    acc[4] = b1.x; acc[5] = b1.y; acc[6] = b1.z; acc[7] = b1.w;
  }
  const u16* base = xin + (size_t)kb * L_ * 128 + dc0;
  #pragma unroll
  for (int dy = -1; dy <= 1; ++dy) {
    int hh = h + dy;
    if (hh < 0 || hh >= H_) continue;
    #pragma unroll
    for (int dx = -1; dx <= 1; ++dx) {
      int ww = w + dx;
      if (ww < 0 || ww >= W_) continue;
      uint4 v = *(const uint4*)(base + (size_t)(hh * W_ + ww) * 128);
      const int t = (dy + 1) * 3 + dx + 1;
      acc[0] += taps[t][dc0 + 0] * bflo(v.x);
      acc[1] += taps[t][dc0 + 1] * bfhi(v.x);
      acc[2] += taps[t][dc0 + 2] * bflo(v.y);
      acc[3] += taps[t][dc0 + 3] * bfhi(v.y);
      acc[4] += taps[t][dc0 + 4] * bflo(v.z);
      acc[5] += taps[t][dc0 + 5] * bfhi(v.z);
      acc[6] += taps[t][dc0 + 6] * bflo(v.w);
      acc[7] += taps[t][dc0 + 7] * bfhi(v.w);
    }
  }
  float u[8];
  u16 ov[8];
  #pragma unroll
  for (int j = 0; j < 8; ++j) { u[j] = silu_(acc[j]); ov[j] = f2bf(u[j]); }
  *(uint4*)(xc + ((size_t)kb * L_ + sp) * 128 + dc0) = *(const uint4*)ov;
  #pragma unroll
  for (int r = 0; r < 10; ++r) {
    float pv = 0.f;
    #pragma unroll
    for (int j = 0; j < 8; ++j) pv += wxs[r][dc0 + j] * u[j];
    part[sl][g][r] = pv;
  }
  __syncthreads();
  if (tid < 160) {
    int sl2 = tid / 10, r = tid - sl2 * 10;
    float s = 0.f;
    #pragma unroll
    for (int g2 = 0; g2 < 16; ++g2) s += part[sl2][g2][r];
    xdbl[((size_t)kb * L_ + blockIdx.x * 16 + sl2) * 16 + r] = s;
  }
}

// ---------------- K6: delta = softplus(dtb + Wdt . dt_row), bf16 ----------------
__global__ __launch_bounds__(256) void k_delta(const float* __restrict__ xdbl,
    const float* __restrict__ Wdt, const float* __restrict__ dtb, u16* __restrict__ delt) {
  __shared__ float xrow[16][8];
  const int kb = blockIdx.y;
  const int k = kb >> 4;
  const int tid = threadIdx.x;
  const int sp0 = blockIdx.x * 16;
  if (tid < 128) {
    int sl = tid >> 3, r = tid & 7;
    xrow[sl][r] = xdbl[((size_t)kb * L_ + sp0 + sl) * 16 + r];
  }
  const int dc = tid & 127, shalf = tid >> 7;
  const float4 w0 = *(const float4*)(Wdt + (size_t)k * 1024 + dc * 8);
  const float4 w1 = *(const float4*)(Wdt + (size_t)k * 1024 + dc * 8 + 4);
  const float db = dtb[k * 128 + dc];
  __syncthreads();
  u16* dst = delt + ((size_t)kb * L_ + sp0 + shalf * 8) * 128 + dc;
  #pragma unroll
  for (int i = 0; i < 8; ++i) {
    const float* r = xrow[shalf * 8 + i];
    float dt = db + w0.x * r[0] + w0.y * r[1] + w0.z * r[2] + w0.w * r[3]
                  + w1.x * r[4] + w1.y * r[5] + w1.z * r[6] + w1.w * r[7];
    float delta = (dt > 20.f) ? dt : __logf(1.f + __expf(dt));
    dst[(size_t)i * 128] = f2bf(delta);
  }
}

// ---------------- K7: scan pass A: segment aggregates (light) ----------------
__global__ __launch_bounds__(256) void k_scan_passA(const u16* __restrict__ xc,
    const u16* __restrict__ delt, const float* __restrict__ xdbl,
    const float* __restrict__ Alog, float* __restrict__ segA, float* __restrict__ segB) {
  const int kb = blockIdx.y;
  const int k = kb >> 4;
  const int s = blockIdx.x * 2 + (threadIdx.x >> 7);
  const int dc = threadIdx.x & 127;
  const float Aa = -__expf(Alog[k * 128 + dc]);
  int sp0, step;
  seg_affine(k, s, sp0, step);
  const u16* up = xc + ((size_t)kb * L_ + sp0) * 128 + dc;
  const u16* dp = delt + ((size_t)kb * L_ + sp0) * 128 + dc;
  const float* xr = xdbl + ((size_t)kb * L_ + sp0) * 16 + 8;
  const int ustep = step * 128, xstep = step * 16;
  float a = 1.f, bacc = 0.f;
  #pragma unroll 4
  for (int i = 0; i < TSEG_; ++i) {
    float Bm = *xr;
    float u = bf2f(*up);
    float delta = bf2f(*dp);
    float dA = __expf(delta * Aa);
    a *= dA;
    bacc = dA * bacc + delta * u * Bm;
    up += ustep; dp += ustep; xr += xstep;
  }
  segA[((size_t)kb * SEG_ + s) * 128 + dc] = a;
  segB[((size_t)kb * SEG_ + s) * 128 + dc] = bacc;
}

// ---------------- K8: scan pass B ----------------
__global__ __launch_bounds__(128) void k_scan_passB(const float* __restrict__ segA,
    const float* __restrict__ segB, float* __restrict__ hpre) {
  const int kb = blockIdx.x;
  const int dc = threadIdx.x;
  float h = 0.f;
  for (int s = 0; s < SEG_; ++s) {
    size_t o = ((size_t)kb * SEG_ + s) * 128 + dc;
    hpre[o] = h;
    h = segA[o] * h + segB[o];
  }
}

// ---------------- K9: scan pass C: apply + fused onorm-LN + silu gate (wave-local) ----------------
__global__ __launch_bounds__(256) void k_scan_passC(u16* __restrict__ xc,
    const u16* __restrict__ delt, const float* __restrict__ xdbl, const u16* __restrict__ zbuf,
    const float* __restrict__ Alog, const float* __restrict__ Dp, const float* __restrict__ hpre,
    const float* __restrict__ ow, const float* __restrict__ ob) {
  const int unit = blockIdx.x * 4 + (threadIdx.x >> 6);   // (kb, s) pair per wave
  const int kb = unit / SEG_;
  const int s = unit - kb * SEG_;
  const int k = kb >> 4;
  const int lane = threadIdx.x & 63;
  const float Aa0 = -__expf(Alog[k * 128 + lane]);
  const float Aa1 = -__expf(Alog[k * 128 + lane + 64]);
  const float Dv0 = Dp[k * 128 + lane],      Dv1 = Dp[k * 128 + lane + 64];
  const float lw0 = ow[k * 128 + lane],      lw1 = ow[k * 128 + lane + 64];
  const float lb0 = ob[k * 128 + lane],      lb1 = ob[k * 128 + lane + 64];
  int sp0, step;
  seg_affine(k, s, sp0, step);
  size_t base = ((size_t)kb * L_ + sp0) * 128 + lane;
  u16* up = xc + base;
  const u16* dp = delt + base;
  const u16* zp = zbuf + base;
  const float* xr = xdbl + ((size_t)kb * L_ + sp0) * 16 + 8;
  const int ustep = step * 128, xstep = step * 16;
  float h0 = hpre[((size_t)kb * SEG_ + s) * 128 + lane];
  float h1 = hpre[((size_t)kb * SEG_ + s) * 128 + lane + 64];
  for (int i = 0; i < TSEG_; ++i) {
    float Bm = xr[0], Cm = xr[1];
    float u0 = bf2f(up[0]), u1 = bf2f(up[64]);
    float d0 = bf2f(dp[0]), d1 = bf2f(dp[64]);
    float z0 = bf2f(zp[0]), z1 = bf2f(zp[64]);
    float dA0 = __expf(d0 * Aa0), dA1 = __expf(d1 * Aa1);
    h0 = dA0 * h0 + d0 * u0 * Bm;
    h1 = dA1 * h1 + d1 * u1 * Bm;
    float y0 = h0 * Cm + Dv0 * u0;
    float y1 = h1 * Cm + Dv1 * u1;
    float s1 = y0 + y1, s2 = y0 * y0 + y1 * y1;
    #pragma unroll
    for (int o = 32; o; o >>= 1) { s1 += __shfl_xor(s1, o, 64); s2 += __shfl_xor(s2, o, 64); }
    float mean = s1 * (1.f / 128.f);
    float rstd = rsqrtf(s2 * (1.f / 128.f) - mean * mean + 1e-5f);
    up[0]  = f2bf(((y0 - mean) * rstd * lw0 + lb0) * silu_(z0));
    up[64] = f2bf(((y1 - mean) * rstd * lw1 + lb1) * silu_(z1));
    up += ustep; dp += ustep; zp += ustep; xr += xstep;
  }
}

// ---------------- K11: fused Wout GEMM (all 4 k) + skip*xh*se + row-LN(512) ----------------
__global__ __launch_bounds__(256) void k_wout_ln(const u16* __restrict__ t,
    const u16* __restrict__ WoutT, const u16* __restrict__ xs, const float* __restrict__ se,
    const float* __restrict__ skip, const float* __restrict__ nw, const float* __restrict__ nb,
    u16* __restrict__ xln) {
  __shared__ u16 As[2048];            // 32 x 64 (swizzled rows of 128B)
  __shared__ u16 Bs[8192];            // 128 x 64
  __shared__ u16 stage[32 * 520];     // 32 rows x 512 cols, stride 520
  const int m0 = blockIdx.x * 32;
  const int tid = threadIdx.x, l = tid & 63, w = tid >> 6;
  const int wm = w >> 1, wn = w & 1;
  const int fr = l & 15, fg = l >> 4;
  for (int k = 0; k < 4; ++k) {
    f32x4 acc[4];
    #pragma unroll
    for (int ni = 0; ni < 4; ++ni) acc[ni] = (f32x4){0.f, 0.f, 0.f, 0.f};
    const u16* Ag = t + ((size_t)k * M_ + m0) * 128;
    const u16* Bg = WoutT + (size_t)k * 16384;
    #pragma unroll
    for (int kk0 = 0; kk0 < 128; kk0 += 64) {
      stage_tile32(As, Ag + kk0, 128);
      stage_tile(Bs, Bg + kk0, 128);
      __syncthreads();
      bf16x8 af[2], bfr[2][4];
      #pragma unroll
      for (int h = 0; h < 2; ++h) {
        af[h] = lds_frag(As, wm * 16 + fr, h * 64 + fg * 16);
        #pragma unroll
        for (int s = 0; s < 4; ++s)
          bfr[h][s] = lds_frag(Bs, wn * 64 + s * 16 + fr, h * 64 + fg * 16);
      }
      #pragma unroll
      for (int h = 0; h < 2; ++h)
        #pragma unroll
        for (int ni = 0; ni < 4; ++ni)
          acc[ni] = __builtin_amdgcn_mfma_f32_16x16x32_bf16(af[h], bfr[h][ni], acc[ni], 0, 0, 0);
      __syncthreads();
    }
    #pragma unroll
    for (int ni = 0; ni < 4; ++ni)
      #pragma unroll
      for (int j = 0; j < 4; ++j)
        stage[(wm * 16 + fg * 4 + j) * 520 + k * 128 + wn * 64 + ni * 16 + fr] = f2bf(acc[ni][j]);
  }
  __syncthreads();
  const int row = tid >> 3, t7 = tid & 7;
  const int m = m0 + row;
  const int b = m / L_;
  const float sk = skip[0];
  float s1 = 0.f, s2 = 0.f;
  #pragma unroll
  for (int i = 0; i < 8; ++i) {
    int col = t7 * 8 + i * 64;
    uint4 cv = *(const uint4*)&stage[row * 520 + col];
    uint4 xv = *(const uint4*)&xs[(size_t)m * 512 + col];
    float4 e0 = *(const float4*)&se[b * 512 + col];
    float4 e1 = *(const float4*)&se[b * 512 + col + 4];
    float o[8];
    o[0] = bflo(cv.x) * sk * bflo(xv.x) * e0.x;
    o[1] = bfhi(cv.x) * sk * bfhi(xv.x) * e0.y;
    o[2] = bflo(cv.y) * sk * bflo(xv.y) * e0.z;
    o[3] = bfhi(cv.y) * sk * bfhi(xv.y) * e0.w;
    o[4] = bflo(cv.z) * sk * bflo(xv.z) * e1.x;
    o[5] = bfhi(cv.z) * sk * bfhi(xv.z) * e1.y;
    o[6] = bflo(cv.w) * sk * bflo(xv.w) * e1.z;
    o[7] = bfhi(cv.w) * sk * bfhi(xv.w) * e1.w;
    u16 ov[8];
    #pragma unroll
    for (int j = 0; j < 8; ++j) { s1 += o[j]; s2 += o[j] * o[j]; ov[j] = f2bf(o[j]); }
    *(uint4*)&stage[row * 520 + col] = *(const uint4*)ov;
  }
  #pragma unroll
  for (int o = 4; o; o >>= 1) { s1 += __shfl_xor(s1, o, 64); s2 += __shfl_xor(s2, o, 64); }
  float mean = s1 * (1.f / C_);
  float rstd = rsqrtf(s2 * (1.f / C_) - mean * mean + 1e-5f);
  #pragma unroll
  for (int i = 0; i < 8; ++i) {
    int col = t7 * 8 + i * 64;
    uint4 cv = *(const uint4*)&stage[row * 520 + col];
    float4 w0 = *(const float4*)&nw[col];
    float4 w1 = *(const float4*)&nw[col + 4];
    float4 b0 = *(const float4*)&nb[col];
    float4 b1 = *(const float4*)&nb[col + 4];
    u16 ov[8];
    ov[0] = f2bf((bflo(cv.x) - mean) * rstd * w0.x + b0.x);
    ov[1] = f2bf((bfhi(cv.x) - mean) * rstd * w0.y + b0.y);
    ov[2] = f2bf((bflo(cv.y) - mean) * rstd * w0.z + b0.z);
    ov[3] = f2bf((bfhi(cv.y) - mean) * rstd * w0.w + b0.w);
    ov[4] = f2bf((bflo(cv.z) - mean) * rstd * w1.x + b1.x);
    ov[5] = f2bf((bfhi(cv.z) - mean) * rstd * w1.y + b1.y);
    ov[6] = f2bf((bflo(cv.w) - mean) * rstd * w1.z + b1.z);
    ov[7] = f2bf((bfhi(cv.w) - mean) * rstd * w1.w + b1.w);
    *(uint4*)&xln[(size_t)m * 512 + col] = *(const uint4*)ov;
  }
}

// ---------------- K13: proj GEMM (MFMA) + bias, XCD-chunk swizzled, transposed write ----------------
__global__ __launch_bounds__(256) void k_gemm_proj(const u16* __restrict__ xln,
    const u16* __restrict__ projwT, const float* __restrict__ projb, float* __restrict__ outp) {
  __shared__ float ldsp[8448];
  u16* As = (u16*)ldsp; u16* Bs = As + 8192;
  const int hw = blockIdx.x;                    // 1152 blocks
  const int lg = (hw & 7) * 144 + (hw >> 3);    // same-A quads -> same XCD
  const int n0 = (lg & 3) * 128;
  const int m0 = (lg >> 2) * 128;
  const int tid = threadIdx.x, l = tid & 63, w = tid >> 6;
  const int wm = w >> 1, wn = w & 1;
  const int fr = l & 15, fg = l >> 4;
  f32x4 acc[4][4];
  #pragma unroll
  for (int mi = 0; mi < 4; ++mi)
    #pragma unroll
    for (int ni = 0; ni < 4; ++ni) acc[mi][ni] = (f32x4){0.f, 0.f, 0.f, 0.f};
  const u16* Ag = xln + (size_t)m0 * 512;
  const u16* Bg = projwT + (size_t)n0 * 512;
  for (int kk0 = 0; kk0 < 512; kk0 += 64) {
    stage_tile(As, Ag + kk0, 512);
    stage_tile(Bs, Bg + kk0, 512);
    __syncthreads();
    bf16x8 af[2][4], bfr[2][4];
    #pragma unroll
    for (int h = 0; h < 2; ++h)
      #pragma unroll
      for (int s = 0; s < 4; ++s) {
        af[h][s]  = lds_frag(As, wm * 64 + s * 16 + fr, h * 64 + fg * 16);
        bfr[h][s] = lds_frag(Bs, wn * 64 + s * 16 + fr, h * 64 + fg * 16);
      }
    #pragma unroll
    for (int h = 0; h < 2; ++h)
      #pragma unroll
      for (int mi = 0; mi < 4; ++mi)
        #pragma unroll
        for (int ni = 0; ni < 4; ++ni)
          acc[mi][ni] = __builtin_amdgcn_mfma_f32_16x16x32_bf16(af[h][mi], bfr[h][ni], acc[mi][ni], 0, 0, 0);
    __syncthreads();
  }
  const int b = m0 / L_, sp0 = m0 % L_;
  #pragma unroll
  for (int half = 0; half < 2; ++half) {
    if (wn == half) {
      #pragma unroll
      for (int ni = 0; ni < 4; ++ni) {
        int nl = ni * 16 + fr;
        float bias = projb[n0 + half * 64 + nl];
        #pragma unroll
        for (int mi = 0; mi < 4; ++mi)
          #pragma unroll
          for (int j = 0; j < 4; ++j)
            ldsp[nl * 132 + wm * 64 + mi * 16 + fg * 4 + j] = acc[mi][ni][j] + bias;
      }
    }
    __syncthreads();
    for (int idx = tid; idx < 64 * 32; idx += 256) {
      int n = idx >> 5, mq = idx & 31;
      float4 v = *(const float4*)&ldsp[n * 132 + mq * 4];
      *(float4*)&outp[((size_t)b * 512 + n0 + half * 64 + n) * L_ + sp0 + mq * 4] = v;
    }
    __syncthreads();
  }
}

extern "C" void kernel_launch(void* const* d_in, const int* in_sizes, int n_in,
                              void* d_out, int out_size, void* d_ws, size_t ws_size,
                              hipStream_t stream) {
  const float* x     = (const float*)d_in[0];
  const float* nw    = (const float*)d_in[1];
  const float* nb    = (const float*)d_in[2];
  const float* fc1w  = (const float*)d_in[3];
  const float* fc1b  = (const float*)d_in[4];
  const float* fc2w  = (const float*)d_in[5];
  const float* fc2b  = (const float*)d_in[6];
  const float* Win   = (const float*)d_in[7];
  const float* convw = (const float*)d_in[8];
  const float* convb = (const float*)d_in[9];
  const float* Wx    = (const float*)d_in[10];
  const float* Wdt   = (const float*)d_in[11];
  const float* dtb   = (const float*)d_in[12];
  const float* Alog  = (const float*)d_in[13];
  const float* Dp    = (const float*)d_in[14];
  const float* onw   = (const float*)d_in[15];
  const float* onb   = (const float*)d_in[16];
  const float* Wout  = (const float*)d_in[17];
  const float* projw = (const float*)d_in[18];
  const float* projb = (const float*)d_in[19];
  const float* skip  = (const float*)d_in[20];
  float* outp = (float*)d_out;

  const size_t BIGE = (size_t)4 * B_ * L_ * 128;   // 18,874,368 elements
  char* p = (char*)d_ws;
  auto carve = [&](size_t bytes) { char* r = p; p += (bytes + 255) & ~(size_t)255; return r; };
  u16*   xs     = (u16*)  carve(BIGE * 2);          // (B,L,C) bf16
  u16*   big1   = (u16*)  carve(BIGE * 2);          // xin -> delta -> xln
  u16*   big2   = (u16*)  carve(BIGE * 2);          // zbuf
  u16*   big3   = (u16*)  carve(BIGE * 2);          // xc -> t (in place)
  float* xdbl   = (float*)carve((size_t)2359296 * 4);
  float* segA   = (float*)carve((size_t)393216 * 4);
  float* segB   = (float*)carve((size_t)393216 * 4);
  float* hpre   = (float*)carve((size_t)393216 * 4);
  float* zpart  = (float*)carve((size_t)B_ * NLB_ * 512 * 4);   // 4.7 MB
  float* z      = (float*)carve((size_t)8192 * 4);
  float* se     = (float*)carve((size_t)8192 * 4);
  u16*   WinT   = (u16*)  carve((size_t)131072 * 2);
  u16*   WoutT  = (u16*)  carve((size_t)65536 * 2);
  u16*   projwT = (u16*)  carve((size_t)262144 * 2);

  k_prep<<<1792, 256, 0, stream>>>(Win, Wout, projw, WinT, WoutT, projwT);
  k_ln_in<<<dim3(NLB_, B_), 256, 0, stream>>>(x, nw, nb, xs, zpart);
  k_colsum_fin<<<dim3(2, B_), 256, 0, stream>>>(zpart, z);
  k_se<<<B_, 256, 0, stream>>>(z, fc1w, fc1b, fc2w, fc2b, se);
  k_gemm_xz<<<2304, 256, 0, stream>>>(xs, WinT, big1, big2);
  k_dwconv<<<dim3(L_ / 16, 64), 256, 0, stream>>>(big1, convw, convb, Wx, big3, xdbl);
  k_delta<<<dim3(L_ / 16, 64), 256, 0, stream>>>(xdbl, Wdt, dtb, big1);
  k_scan_passA<<<dim3(SEG_ / 2, 64), 256, 0, stream>>>(big3, big1, xdbl, Alog, segA, segB);
  k_scan_passB<<<64, 128, 0, stream>>>(segA, segB, hpre);
  k_scan_passC<<<SEG_ * 64 / 4, 256, 0, stream>>>(big3, big1, xdbl, big2, Alog, Dp, hpre, onw, onb);
  k_wout_ln<<<M_ / 32, 256, 0, stream>>>(big3, WoutT, xs, se, skip, nw, nb, big1);
  k_gemm_proj<<<1152, 256, 0, stream>>>(big1, projwT, projb, outp);
}

// Round 15
// 299.810 us; speedup vs baseline: 1.0300x; 1.0164x over previous
//
#include <hip/hip_runtime.h>
#include <math.h>

#define DEV static __device__ __forceinline__

typedef unsigned int  u32;
typedef unsigned short u16;

using bf16x8 = __attribute__((ext_vector_type(8))) __bf16;
using f32x4  = __attribute__((ext_vector_type(4))) float;

static constexpr int B_ = 16;
static constexpr int C_ = 512;
static constexpr int H_ = 48;
static constexpr int W_ = 48;
static constexpr int L_ = 2304;      // H*W
static constexpr int M_ = B_ * L_;   // 36864
static constexpr int SEG_ = 48;      // scan segments (2304 = 48*48)
static constexpr int TSEG_ = 48;
static constexpr int NLB_ = 144;     // ln_in blocks per batch (L/16)

DEV float silu_(float v) { return v / (1.f + __expf(-v)); }
DEV float bflo(u32 p) { return __uint_as_float(p << 16); }
DEV float bfhi(u32 p) { return __uint_as_float(p & 0xffff0000u); }
DEV float bf2f(u16 v) { return __uint_as_float(((u32)v) << 16); }
DEV u16 f2bf(float f) { u32 u = __float_as_uint(f); u32 r = u + 0x7fffu + ((u >> 16) & 1u); return (u16)(r >> 16); }

// direction k, segment s (TSEG=48): sp = sp0 + step*i, i in [0,48)
DEV void seg_affine(int k, int s, int& sp0, int& step) {
  if (k == 0)      { sp0 = 48 * s;        step = 1;   }
  else if (k == 1) { sp0 = 2303 - 48 * s; step = -1;  }
  else if (k == 2) { sp0 = s;             step = 48;  }
  else             { sp0 = 2303 - s;      step = -48; }
}

// ================= MFMA GEMM helpers (tiles with T2 XOR swizzle) =================
DEV void stage_tile(u16* Ls, const u16* __restrict__ g, int ld) {
  const int tid = threadIdx.x;
  #pragma unroll
  for (int i = 0; i < 4; ++i) {
    int c = i * 256 + tid;
    int row = c >> 3, slot = c & 7;
    uint4 v = *(const uint4*)(g + (size_t)row * ld + slot * 8);
    int b = row * 128 + ((slot * 16) ^ ((row & 7) << 4));
    *(uint4*)((char*)Ls + b) = v;
  }
}

DEV void stage_tile32(u16* Ls, const u16* __restrict__ g, int ld) {
  const int c = threadIdx.x;          // 32 rows x 8 slots = 256 chunks
  int row = c >> 3, slot = c & 7;
  uint4 v = *(const uint4*)(g + (size_t)row * ld + slot * 8);
  int b = row * 128 + ((slot * 16) ^ ((row & 7) << 4));
  *(uint4*)((char*)Ls + b) = v;
}

DEV bf16x8 lds_frag(const u16* Ls, int row, int kbyte) {
  int b = row * 128 + (kbyte ^ ((row & 7) << 4));
  return *(const bf16x8*)((const char*)Ls + b);
}

// ---------------- K0: weight prep: transpose + bf16 convert ----------------
__global__ __launch_bounds__(256) void k_prep(const float* __restrict__ Win,
    const float* __restrict__ Wout, const float* __restrict__ projw,
    u16* __restrict__ WinT, u16* __restrict__ WoutT, u16* __restrict__ projwT) {
  int id = blockIdx.x * 256 + threadIdx.x;
  if (id < 131072) {
    int k = id >> 15, rem = id & 32767;
    int r = rem >> 8, n = rem & 255;
    WinT[(k << 15) + n * 128 + r] = f2bf(Win[id]);
  } else if (id < 196608) {
    int t = id - 131072;
    int k = t >> 14, rem = t & 16383;
    int r = rem >> 7, n = rem & 127;
    WoutT[(k << 14) + n * 128 + r] = f2bf(Wout[t]);
  } else {
    int t = id - 196608;
    int r = t >> 9, n = t & 511;
    projwT[n * 512 + r] = f2bf(projw[t]);
  }
}

// ---------------- K1: layernorm over C of x (B,L,C) + fused SE column partials ----------------
__global__ __launch_bounds__(256) void k_ln_in(const float* __restrict__ x,
    const float* __restrict__ w, const float* __restrict__ bia, u16* __restrict__ xs,
    float* __restrict__ zpart) {
  __shared__ float tile[16 * 513];
  __shared__ float smean[16], srstd[16];
  const int b = blockIdx.y;
  const int l0 = blockIdx.x * 16;
  const int tid = threadIdx.x;
  const float* xb = x + (size_t)b * C_ * L_;
  #pragma unroll
  for (int i = 0; i < 8; ++i) {
    int idx4 = i * 256 + tid;
    int c = idx4 >> 2, lt4 = (idx4 & 3) * 4;
    float4 v = *(const float4*)(xb + (size_t)c * L_ + l0 + lt4);
    tile[(lt4 + 0) * 513 + c] = v.x;
    tile[(lt4 + 1) * 513 + c] = v.y;
    tile[(lt4 + 2) * 513 + c] = v.z;
    tile[(lt4 + 3) * 513 + c] = v.w;
  }
  __syncthreads();
  {
    const int j = tid & 15, g = tid >> 4;
    float s1 = 0.f, s2 = 0.f;
    #pragma unroll
    for (int i = 0; i < 32; ++i) {
      float v = tile[g * 513 + j + i * 16];
      s1 += v; s2 += v * v;
    }
    #pragma unroll
    for (int o = 8; o; o >>= 1) { s1 += __shfl_xor(s1, o, 16); s2 += __shfl_xor(s2, o, 16); }
    if (j == 0) {
      float mean = s1 * (1.f / C_);
      float var = s2 * (1.f / C_) - mean * mean;
      smean[g] = mean;
      srstd[g] = rsqrtf(var + 1e-5f);
    }
  }
  __syncthreads();
  float p0 = 0.f, p1 = 0.f;
  for (int idx = tid; idx < 16 * C_; idx += 256) {
    int lt = idx >> 9, c = idx & 511;
    float v = (tile[lt * 513 + c] - smean[lt]) * srstd[lt] * w[c] + bia[c];
    xs[((size_t)b * L_ + l0 + lt) * C_ + c] = f2bf(v);
    if (c == tid) p0 += v; else p1 += v;
  }
  float* zp = zpart + ((size_t)b * NLB_ + blockIdx.x) * 512;
  zp[tid] = p0;
  zp[tid + 256] = p1;
}

// ---------------- K2: SE column partial merge (6-way parallel) ----------------
__global__ __launch_bounds__(256) void k_colsum_fin(const float* __restrict__ zpart, float* __restrict__ z6) {
  const int c = blockIdx.x * 256 + threadIdx.x;
  const int b = blockIdx.y;
  const int ch = blockIdx.z;                 // 6 chunks of 24
  float acc = 0.f;
  for (int s = ch * 24; s < ch * 24 + 24; ++s) acc += zpart[((size_t)b * NLB_ + s) * 512 + c];
  z6[((size_t)b * 6 + ch) * 512 + c] = acc;
}

// ---------------- K3: SE MLP (merges 6 partials) ----------------
__global__ __launch_bounds__(256) void k_se(const float* __restrict__ z6,
    const float* __restrict__ fc1w, const float* __restrict__ fc1b,
    const float* __restrict__ fc2w, const float* __restrict__ fc2b, float* __restrict__ se) {
  __shared__ float zs[512];
  __shared__ float hs[32];
  const int b = blockIdx.x, tid = threadIdx.x;
  {
    float a0 = 0.f, a1 = 0.f;
    #pragma unroll
    for (int ch = 0; ch < 6; ++ch) {
      a0 += z6[((size_t)b * 6 + ch) * 512 + tid];
      a1 += z6[((size_t)b * 6 + ch) * 512 + tid + 256];
    }
    zs[tid] = a0 * (1.f / L_);
    zs[tid + 256] = a1 * (1.f / L_);
  }
  __syncthreads();
  if (tid < 32) {
    float a = fc1b[tid];
    for (int c = 0; c < 512; ++c) a += zs[c] * fc1w[c * 32 + tid];
    hs[tid] = fmaxf(a, 0.f);
  }
  __syncthreads();
  for (int c = tid; c < 512; c += 256) {
    float a = fc2b[c];
    #pragma unroll
    for (int r = 0; r < 32; ++r) a += hs[r] * fc2w[r * 512 + c];
    se[b * C_ + c] = 1.f / (1.f + __expf(-a));
  }
}

// ---------------- K4: xz GEMM (MFMA), XCD-chunk swizzled 1D grid ----------------
__global__ __launch_bounds__(256) void k_gemm_xz(const u16* __restrict__ xs,
    const u16* __restrict__ WinT, u16* __restrict__ xin, u16* __restrict__ zbuf) {
  __shared__ u16 lds[16384];
  u16* As = lds; u16* Bs = lds + 8192;
  const int hw = blockIdx.x;                         // 2304 blocks
  const int lg = (hw & 7) * 288 + (hw >> 3);         // same-A pairs -> same XCD
  const int nb = lg & 1;
  const int m0 = ((lg >> 1) % 288) * 128;
  const int k = lg / 576;
  const int tid = threadIdx.x, l = tid & 63, w = tid >> 6;
  const int wm = w >> 1, wn = w & 1;
  const int fr = l & 15, fg = l >> 4;
  f32x4 acc[4][4];
  #pragma unroll
  for (int mi = 0; mi < 4; ++mi)
    #pragma unroll
    for (int ni = 0; ni < 4; ++ni) acc[mi][ni] = (f32x4){0.f, 0.f, 0.f, 0.f};
  const u16* Ag = xs + (size_t)m0 * 512 + k * 128;
  const u16* Bg = WinT + (size_t)k * 32768 + (size_t)nb * 16384;
  #pragma unroll
  for (int kk0 = 0; kk0 < 128; kk0 += 64) {
    stage_tile(As, Ag + kk0, 512);
    stage_tile(Bs, Bg + kk0, 128);
    __syncthreads();
    bf16x8 af[2][4], bfr[2][4];
    #pragma unroll
    for (int h = 0; h < 2; ++h)
      #pragma unroll
      for (int s = 0; s < 4; ++s) {
        af[h][s]  = lds_frag(As, wm * 64 + s * 16 + fr, h * 64 + fg * 16);
        bfr[h][s] = lds_frag(Bs, wn * 64 + s * 16 + fr, h * 64 + fg * 16);
      }
    #pragma unroll
    for (int h = 0; h < 2; ++h)
      #pragma unroll
      for (int mi = 0; mi < 4; ++mi)
        #pragma unroll
        for (int ni = 0; ni < 4; ++ni)
          acc[mi][ni] = __builtin_amdgcn_mfma_f32_16x16x32_bf16(af[h][mi], bfr[h][ni], acc[mi][ni], 0, 0, 0);
    __syncthreads();
  }
  #pragma unroll
  for (int mi = 0; mi < 4; ++mi)
    #pragma unroll
    for (int ni = 0; ni < 4; ++ni)
      #pragma unroll
      for (int j = 0; j < 4; ++j)
        lds[(wm * 64 + mi * 16 + fg * 4 + j) * 128 + wn * 64 + ni * 16 + fr] = f2bf(acc[mi][ni][j]);
  __syncthreads();
  u16* dst = (nb == 0 ? xin : zbuf) + ((size_t)k * M_ + m0) * 128;
  for (int idx = tid; idx < 128 * 16; idx += 256) {
    int row = idx >> 4, q = idx & 15;
    *(uint4*)&dst[(size_t)row * 128 + q * 8] = *(const uint4*)&lds[row * 128 + q * 8];
  }
}

// ---------------- K5: fused depthwise 3x3 conv + bias + silu + x_dbl (frozen R12 form) ----------------
// xdbl compacted to 8 floats/row (dt rows only); Bm/Cm go to compact bc[sp][2] (1.2 MB, L1/L2-hot)
__global__ __launch_bounds__(256) void k_dwconv(const u16* __restrict__ xin,
    const float* __restrict__ cw, const float* __restrict__ cb, const float* __restrict__ Wx,
    u16* __restrict__ xc, float* __restrict__ xdbl, float* __restrict__ bc) {
  __shared__ float taps[9][128];
  __shared__ float wxs[10][128];
  __shared__ float part[16][16][10];   // [sl][g][r]
  const int kb = blockIdx.y;
  const int k = kb >> 4;
  const int tid = threadIdx.x;
  for (int i = tid; i < 1152; i += 256) {
    int dc = i / 9, t = i - dc * 9;
    taps[t][dc] = cw[((size_t)k * 128 + dc) * 9 + t];
  }
  for (int i = tid; i < 1280; i += 256) wxs[i >> 7][i & 127] = Wx[(size_t)k * 1280 + i];
  __syncthreads();
  const int sl = tid >> 4, g = tid & 15;
  const int sp = blockIdx.x * 16 + sl;
  const int h = sp / W_, w = sp % W_;
  const int dc0 = g * 8;
  float acc[8];
  {
    float4 b0 = *(const float4*)(cb + k * 128 + dc0);
    float4 b1 = *(const float4*)(cb + k * 128 + dc0 + 4);
    acc[0] = b0.x; acc[1] = b0.y; acc[2] = b0.z; acc[3] = b0.w;
    acc[4] = b1.x; acc[5] = b1.y; acc[6] = b1.z; acc[7] = b1.w;
  }
  const u16* base = xin + (size_t)kb * L_ * 128 + dc0;
  #pragma unroll
  for (int dy = -1; dy <= 1; ++dy) {
    int hh = h + dy;
    if (hh < 0 || hh >= H_) continue;
    #pragma unroll
    for (int dx = -1; dx <= 1; ++dx) {
      int ww = w + dx;
      if (ww < 0 || ww >= W_) continue;
      uint4 v = *(const uint4*)(base + (size_t)(hh * W_ + ww) * 128);
      const int t = (dy + 1) * 3 + dx + 1;
      acc[0] += taps[t][dc0 + 0] * bflo(v.x);
      acc[1] += taps[t][dc0 + 1] * bfhi(v.x);
      acc[2] += taps[t][dc0 + 2] * bflo(v.y);
      acc[3] += taps[t][dc0 + 3] * bfhi(v.y);
      acc[4] += taps[t][dc0 + 4] * bflo(v.z);
      acc[5] += taps[t][dc0 + 5] * bfhi(v.z);
      acc[6] += taps[t][dc0 + 6] * bflo(v.w);
      acc[7] += taps[t][dc0 + 7] * bfhi(v.w);
    }
  }
  float u[8];
  u16 ov[8];
  #pragma unroll
  for (int j = 0; j < 8; ++j) { u[j] = silu_(acc[j]); ov[j] = f2bf(u[j]); }
  *(uint4*)(xc + ((size_t)kb * L_ + sp) * 128 + dc0) = *(const uint4*)ov;
  #pragma unroll
  for (int r = 0; r < 10; ++r) {
    float pv = 0.f;
    #pragma unroll
    for (int j = 0; j < 8; ++j) pv += wxs[r][dc0 + j] * u[j];
    part[sl][g][r] = pv;
  }
  __syncthreads();
  if (tid < 160) {
    int sl2 = tid / 10, r = tid - sl2 * 10;
    float s = 0.f;
    #pragma unroll
    for (int g2 = 0; g2 < 16; ++g2) s += part[sl2][g2][r];
    size_t spg = (size_t)kb * L_ + blockIdx.x * 16 + sl2;
    if (r < 8) xdbl[spg * 8 + r] = s;
    else       bc[spg * 2 + (r - 8)] = s;
  }
}

// ---------------- K6: delta = softplus(dtb + Wdt . dt_row), bf16 ----------------
__global__ __launch_bounds__(256) void k_delta(const float* __restrict__ xdbl,
    const float* __restrict__ Wdt, const float* __restrict__ dtb, u16* __restrict__ delt) {
  __shared__ float xrow[16][8];
  const int kb = blockIdx.y;
  const int k = kb >> 4;
  const int tid = threadIdx.x;
  const int sp0 = blockIdx.x * 16;
  if (tid < 128) {
    int sl = tid >> 3, r = tid & 7;
    xrow[sl][r] = xdbl[((size_t)kb * L_ + sp0 + sl) * 8 + r];
  }
  const int dc = tid & 127, shalf = tid >> 7;
  const float4 w0 = *(const float4*)(Wdt + (size_t)k * 1024 + dc * 8);
  const float4 w1 = *(const float4*)(Wdt + (size_t)k * 1024 + dc * 8 + 4);
  const float db = dtb[k * 128 + dc];
  __syncthreads();
  u16* dst = delt + ((size_t)kb * L_ + sp0 + shalf * 8) * 128 + dc;
  #pragma unroll
  for (int i = 0; i < 8; ++i) {
    const float* r = xrow[shalf * 8 + i];
    float dt = db + w0.x * r[0] + w0.y * r[1] + w0.z * r[2] + w0.w * r[3]
                  + w1.x * r[4] + w1.y * r[5] + w1.z * r[6] + w1.w * r[7];
    float delta = (dt > 20.f) ? dt : __logf(1.f + __expf(dt));
    dst[(size_t)i * 128] = f2bf(delta);
  }
}

// ---------------- K7: scan pass A: segment aggregates (light, compact bc) ----------------
__global__ __launch_bounds__(256) void k_scan_passA(const u16* __restrict__ xc,
    const u16* __restrict__ delt, const float* __restrict__ bc,
    const float* __restrict__ Alog, float* __restrict__ segA, float* __restrict__ segB) {
  const int kb = blockIdx.y;
  const int k = kb >> 4;
  const int s = blockIdx.x * 2 + (threadIdx.x >> 7);
  const int dc = threadIdx.x & 127;
  const float Aa = -__expf(Alog[k * 128 + dc]);
  int sp0, step;
  seg_affine(k, s, sp0, step);
  const u16* up = xc + ((size_t)kb * L_ + sp0) * 128 + dc;
  const u16* dp = delt + ((size_t)kb * L_ + sp0) * 128 + dc;
  const float* bp = bc + ((size_t)kb * L_ + sp0) * 2;
  const int ustep = step * 128, bstep = step * 2;
  float a = 1.f, bacc = 0.f;
  #pragma unroll 4
  for (int i = 0; i < TSEG_; ++i) {
    float Bm = bp[0];
    float u = bf2f(*up);
    float delta = bf2f(*dp);
    float dA = __expf(delta * Aa);
    a *= dA;
    bacc = dA * bacc + delta * u * Bm;
    up += ustep; dp += ustep; bp += bstep;
  }
  segA[((size_t)kb * SEG_ + s) * 128 + dc] = a;
  segB[((size_t)kb * SEG_ + s) * 128 + dc] = bacc;
}

// ---------------- K8: scan pass B ----------------
__global__ __launch_bounds__(128) void k_scan_passB(const float* __restrict__ segA,
    const float* __restrict__ segB, float* __restrict__ hpre) {
  const int kb = blockIdx.x;
  const int dc = threadIdx.x;
  float h = 0.f;
  for (int s = 0; s < SEG_; ++s) {
    size_t o = ((size_t)kb * SEG_ + s) * 128 + dc;
    hpre[o] = h;
    h = segA[o] * h + segB[o];
  }
}

// ---------------- K9: scan pass C: apply + fused onorm-LN + silu gate (wave-local) ----------------
__global__ __launch_bounds__(256) void k_scan_passC(u16* __restrict__ xc,
    const u16* __restrict__ delt, const float* __restrict__ bc, const u16* __restrict__ zbuf,
    const float* __restrict__ Alog, const float* __restrict__ Dp, const float* __restrict__ hpre,
    const float* __restrict__ ow, const float* __restrict__ ob) {
  const int unit = blockIdx.x * 4 + (threadIdx.x >> 6);   // (kb, s) pair per wave
  const int kb = unit / SEG_;
  const int s = unit - kb * SEG_;
  const int k = kb >> 4;
  const int lane = threadIdx.x & 63;
  const float Aa0 = -__expf(Alog[k * 128 + lane]);
  const float Aa1 = -__expf(Alog[k * 128 + lane + 64]);
  const float Dv0 = Dp[k * 128 + lane],      Dv1 = Dp[k * 128 + lane + 64];
  const float lw0 = ow[k * 128 + lane],      lw1 = ow[k * 128 + lane + 64];
  const float lb0 = ob[k * 128 + lane],      lb1 = ob[k * 128 + lane + 64];
  int sp0, step;
  seg_affine(k, s, sp0, step);
  size_t base = ((size_t)kb * L_ + sp0) * 128 + lane;
  u16* up = xc + base;
  const u16* dp = delt + base;
  const u16* zp = zbuf + base;
  const float* bp = bc + ((size_t)kb * L_ + sp0) * 2;
  const int ustep = step * 128, bstep = step * 2;
  float h0 = hpre[((size_t)kb * SEG_ + s) * 128 + lane];
  float h1 = hpre[((size_t)kb * SEG_ + s) * 128 + lane + 64];
  for (int i = 0; i < TSEG_; ++i) {
    float Bm = bp[0], Cm = bp[1];
    float u0 = bf2f(up[0]), u1 = bf2f(up[64]);
    float d0 = bf2f(dp[0]), d1 = bf2f(dp[64]);
    float z0 = bf2f(zp[0]), z1 = bf2f(zp[64]);
    float dA0 = __expf(d0 * Aa0), dA1 = __expf(d1 * Aa1);
    h0 = dA0 * h0 + d0 * u0 * Bm;
    h1 = dA1 * h1 + d1 * u1 * Bm;
    float y0 = h0 * Cm + Dv0 * u0;
    float y1 = h1 * Cm + Dv1 * u1;
    float s1 = y0 + y1, s2 = y0 * y0 + y1 * y1;
    #pragma unroll
    for (int o = 32; o; o >>= 1) { s1 += __shfl_xor(s1, o, 64); s2 += __shfl_xor(s2, o, 64); }
    float mean = s1 * (1.f / 128.f);
    float rstd = rsqrtf(s2 * (1.f / 128.f) - mean * mean + 1e-5f);
    up[0]  = f2bf(((y0 - mean) * rstd * lw0 + lb0) * silu_(z0));
    up[64] = f2bf(((y1 - mean) * rstd * lw1 + lb1) * silu_(z1));
    up += ustep; dp += ustep; zp += ustep; bp += bstep;
  }
}

// ---------------- K11: fused Wout GEMM (all 4 k) + skip*xh*se + row-LN(512) ----------------
__global__ __launch_bounds__(256) void k_wout_ln(const u16* __restrict__ t,
    const u16* __restrict__ WoutT, const u16* __restrict__ xs, const float* __restrict__ se,
    const float* __restrict__ skip, const float* __restrict__ nw, const float* __restrict__ nb,
    u16* __restrict__ xln) {
  __shared__ u16 As[2048];            // 32 x 64 (swizzled rows of 128B)
  __shared__ u16 Bs[8192];            // 128 x 64
  __shared__ u16 stage[32 * 520];     // 32 rows x 512 cols, stride 520
  const int m0 = blockIdx.x * 32;
  const int tid = threadIdx.x, l = tid & 63, w = tid >> 6;
  const int wm = w >> 1, wn = w & 1;
  const int fr = l & 15, fg = l >> 4;
  for (int k = 0; k < 4; ++k) {
    f32x4 acc[4];
    #pragma unroll
    for (int ni = 0; ni < 4; ++ni) acc[ni] = (f32x4){0.f, 0.f, 0.f, 0.f};
    const u16* Ag = t + ((size_t)k * M_ + m0) * 128;
    const u16* Bg = WoutT + (size_t)k * 16384;
    #pragma unroll
    for (int kk0 = 0; kk0 < 128; kk0 += 64) {
      stage_tile32(As, Ag + kk0, 128);
      stage_tile(Bs, Bg + kk0, 128);
      __syncthreads();
      bf16x8 af[2], bfr[2][4];
      #pragma unroll
      for (int h = 0; h < 2; ++h) {
        af[h] = lds_frag(As, wm * 16 + fr, h * 64 + fg * 16);
        #pragma unroll
        for (int s = 0; s < 4; ++s)
          bfr[h][s] = lds_frag(Bs, wn * 64 + s * 16 + fr, h * 64 + fg * 16);
      }
      #pragma unroll
      for (int h = 0; h < 2; ++h)
        #pragma unroll
        for (int ni = 0; ni < 4; ++ni)
          acc[ni] = __builtin_amdgcn_mfma_f32_16x16x32_bf16(af[h], bfr[h][ni], acc[ni], 0, 0, 0);
      __syncthreads();
    }
    #pragma unroll
    for (int ni = 0; ni < 4; ++ni)
      #pragma unroll
      for (int j = 0; j < 4; ++j)
        stage[(wm * 16 + fg * 4 + j) * 520 + k * 128 + wn * 64 + ni * 16 + fr] = f2bf(acc[ni][j]);
  }
  __syncthreads();
  const int row = tid >> 3, t7 = tid & 7;
  const int m = m0 + row;
  const int b = m / L_;
  const float sk = skip[0];
  float s1 = 0.f, s2 = 0.f;
  #pragma unroll
  for (int i = 0; i < 8; ++i) {
    int col = t7 * 8 + i * 64;
    uint4 cv = *(const uint4*)&stage[row * 520 + col];
    uint4 xv = *(const uint4*)&xs[(size_t)m * 512 + col];
    float4 e0 = *(const float4*)&se[b * 512 + col];
    float4 e1 = *(const float4*)&se[b * 512 + col + 4];
    float o[8];
    o[0] = bflo(cv.x) * sk * bflo(xv.x) * e0.x;
    o[1] = bfhi(cv.x) * sk * bfhi(xv.x) * e0.y;
    o[2] = bflo(cv.y) * sk * bflo(xv.y) * e0.z;
    o[3] = bfhi(cv.y) * sk * bfhi(xv.y) * e0.w;
    o[4] = bflo(cv.z) * sk * bflo(xv.z) * e1.x;
    o[5] = bfhi(cv.z) * sk * bfhi(xv.z) * e1.y;
    o[6] = bflo(cv.w) * sk * bflo(xv.w) * e1.z;
    o[7] = bfhi(cv.w) * sk * bfhi(xv.w) * e1.w;
    u16 ov[8];
    #pragma unroll
    for (int j = 0; j < 8; ++j) { s1 += o[j]; s2 += o[j] * o[j]; ov[j] = f2bf(o[j]); }
    *(uint4*)&stage[row * 520 + col] = *(const uint4*)ov;
  }
  #pragma unroll
  for (int o = 4; o; o >>= 1) { s1 += __shfl_xor(s1, o, 64); s2 += __shfl_xor(s2, o, 64); }
  float mean = s1 * (1.f / C_);
  float rstd = rsqrtf(s2 * (1.f / C_) - mean * mean + 1e-5f);
  #pragma unroll
  for (int i = 0; i < 8; ++i) {
    int col = t7 * 8 + i * 64;
    uint4 cv = *(const uint4*)&stage[row * 520 + col];
    float4 w0 = *(const float4*)&nw[col];
    float4 w1 = *(const float4*)&nw[col + 4];
    float4 b0 = *(const float4*)&nb[col];
    float4 b1 = *(const float4*)&nb[col + 4];
    u16 ov[8];
    ov[0] = f2bf((bflo(cv.x) - mean) * rstd * w0.x + b0.x);
    ov[1] = f2bf((bfhi(cv.x) - mean) * rstd * w0.y + b0.y);
    ov[2] = f2bf((bflo(cv.y) - mean) * rstd * w0.z + b0.z);
    ov[3] = f2bf((bfhi(cv.y) - mean) * rstd * w0.w + b0.w);
    ov[4] = f2bf((bflo(cv.z) - mean) * rstd * w1.x + b1.x);
    ov[5] = f2bf((bfhi(cv.z) - mean) * rstd * w1.y + b1.y);
    ov[6] = f2bf((bflo(cv.w) - mean) * rstd * w1.z + b1.z);
    ov[7] = f2bf((bfhi(cv.w) - mean) * rstd * w1.w + b1.w);
    *(uint4*)&xln[(size_t)m * 512 + col] = *(const uint4*)ov;
  }
}

// ---------------- K13: proj GEMM (MFMA) + bias, XCD-chunk swizzled, transposed write ----------------
__global__ __launch_bounds__(256) void k_gemm_proj(const u16* __restrict__ xln,
    const u16* __restrict__ projwT, const float* __restrict__ projb, float* __restrict__ outp) {
  __shared__ float ldsp[8448];
  u16* As = (u16*)ldsp; u16* Bs = As + 8192;
  const int hw = blockIdx.x;                    // 1152 blocks
  const int lg = (hw & 7) * 144 + (hw >> 3);    // same-A quads -> same XCD
  const int n0 = (lg & 3) * 128;
  const int m0 = (lg >> 2) * 128;
  const int tid = threadIdx.x, l = tid & 63, w = tid >> 6;
  const int wm = w >> 1, wn = w & 1;
  const int fr = l & 15, fg = l >> 4;
  f32x4 acc[4][4];
  #pragma unroll
  for (int mi = 0; mi < 4; ++mi)
    #pragma unroll
    for (int ni = 0; ni < 4; ++ni) acc[mi][ni] = (f32x4){0.f, 0.f, 0.f, 0.f};
  const u16* Ag = xln + (size_t)m0 * 512;
  const u16* Bg = projwT + (size_t)n0 * 512;
  for (int kk0 = 0; kk0 < 512; kk0 += 64) {
    stage_tile(As, Ag + kk0, 512);
    stage_tile(Bs, Bg + kk0, 512);
    __syncthreads();
    bf16x8 af[2][4], bfr[2][4];
    #pragma unroll
    for (int h = 0; h < 2; ++h)
      #pragma unroll
      for (int s = 0; s < 4; ++s) {
        af[h][s]  = lds_frag(As, wm * 64 + s * 16 + fr, h * 64 + fg * 16);
        bfr[h][s] = lds_frag(Bs, wn * 64 + s * 16 + fr, h * 64 + fg * 16);
      }
    #pragma unroll
    for (int h = 0; h < 2; ++h)
      #pragma unroll
      for (int mi = 0; mi < 4; ++mi)
        #pragma unroll
        for (int ni = 0; ni < 4; ++ni)
          acc[mi][ni] = __builtin_amdgcn_mfma_f32_16x16x32_bf16(af[h][mi], bfr[h][ni], acc[mi][ni], 0, 0, 0);
    __syncthreads();
  }
  const int b = m0 / L_, sp0 = m0 % L_;
  #pragma unroll
  for (int half = 0; half < 2; ++half) {
    if (wn == half) {
      #pragma unroll
      for (int ni = 0; ni < 4; ++ni) {
        int nl = ni * 16 + fr;
        float bias = projb[n0 + half * 64 + nl];
        #pragma unroll
        for (int mi = 0; mi < 4; ++mi)
          #pragma unroll
          for (int j = 0; j < 4; ++j)
            ldsp[nl * 132 + wm * 64 + mi * 16 + fg * 4 + j] = acc[mi][ni][j] + bias;
      }
    }
    __syncthreads();
    for (int idx = tid; idx < 64 * 32; idx += 256) {
      int n = idx >> 5, mq = idx & 31;
      float4 v = *(const float4*)&ldsp[n * 132 + mq * 4];
      *(float4*)&outp[((size_t)b * 512 + n0 + half * 64 + n) * L_ + sp0 + mq * 4] = v;
    }
    __syncthreads();
  }
}

extern "C" void kernel_launch(void* const* d_in, const int* in_sizes, int n_in,
                              void* d_out, int out_size, void* d_ws, size_t ws_size,
                              hipStream_t stream) {
  const float* x     = (const float*)d_in[0];
  const float* nw    = (const float*)d_in[1];
  const float* nb    = (const float*)d_in[2];
  const float* fc1w  = (const float*)d_in[3];
  const float* fc1b  = (const float*)d_in[4];
  const float* fc2w  = (const float*)d_in[5];
  const float* fc2b  = (const float*)d_in[6];
  const float* Win   = (const float*)d_in[7];
  const float* convw = (const float*)d_in[8];
  const float* convb = (const float*)d_in[9];
  const float* Wx    = (const float*)d_in[10];
  const float* Wdt   = (const float*)d_in[11];
  const float* dtb   = (const float*)d_in[12];
  const float* Alog  = (const float*)d_in[13];
  const float* Dp    = (const float*)d_in[14];
  const float* onw   = (const float*)d_in[15];
  const float* onb   = (const float*)d_in[16];
  const float* Wout  = (const float*)d_in[17];
  const float* projw = (const float*)d_in[18];
  const float* projb = (const float*)d_in[19];
  const float* skip  = (const float*)d_in[20];
  float* outp = (float*)d_out;

  const size_t BIGE = (size_t)4 * B_ * L_ * 128;   // 18,874,368 elements
  char* p = (char*)d_ws;
  auto carve = [&](size_t bytes) { char* r = p; p += (bytes + 255) & ~(size_t)255; return r; };
  u16*   xs     = (u16*)  carve(BIGE * 2);          // (B,L,C) bf16
  u16*   big1   = (u16*)  carve(BIGE * 2);          // xin -> delta -> xln
  u16*   big2   = (u16*)  carve(BIGE * 2);          // zbuf
  u16*   big3   = (u16*)  carve(BIGE * 2);          // xc -> t (in place)
  float* xdbl   = (float*)carve((size_t)1179648 * 4);   // [kb][sp][8] dt rows
  float* bc     = (float*)carve((size_t)294912 * 4);    // [kb][sp][2] Bm,Cm
  float* segA   = (float*)carve((size_t)393216 * 4);
  float* segB   = (float*)carve((size_t)393216 * 4);
  float* hpre   = (float*)carve((size_t)393216 * 4);
  float* zpart  = (float*)carve((size_t)B_ * NLB_ * 512 * 4);   // 4.7 MB
  float* z6     = (float*)carve((size_t)B_ * 6 * 512 * 4);
  float* se     = (float*)carve((size_t)8192 * 4);
  u16*   WinT   = (u16*)  carve((size_t)131072 * 2);
  u16*   WoutT  = (u16*)  carve((size_t)65536 * 2);
  u16*   projwT = (u16*)  carve((size_t)262144 * 2);

  k_prep<<<1792, 256, 0, stream>>>(Win, Wout, projw, WinT, WoutT, projwT);
  k_ln_in<<<dim3(NLB_, B_), 256, 0, stream>>>(x, nw, nb, xs, zpart);
  k_colsum_fin<<<dim3(2, B_, 6), 256, 0, stream>>>(zpart, z6);
  k_se<<<B_, 256, 0, stream>>>(z6, fc1w, fc1b, fc2w, fc2b, se);
  k_gemm_xz<<<2304, 256, 0, stream>>>(xs, WinT, big1, big2);
  k_dwconv<<<dim3(L_ / 16, 64), 256, 0, stream>>>(big1, convw, convb, Wx, big3, xdbl, bc);
  k_delta<<<dim3(L_ / 16, 64), 256, 0, stream>>>(xdbl, Wdt, dtb, big1);
  k_scan_passA<<<dim3(SEG_ / 2, 64), 256, 0, stream>>>(big3, big1, bc, Alog, segA, segB);
  k_scan_passB<<<64, 128, 0, stream>>>(segA, segB, hpre);
  k_scan_passC<<<SEG_ * 64 / 4, 256, 0, stream>>>(big3, big1, bc, big2, Alog, Dp, hpre, onw, onb);
  k_wout_ln<<<M_ / 32, 256, 0, stream>>>(big3, WoutT, xs, se, skip, nw, nb, big1);
  k_gemm_proj<<<1152, 256, 0, stream>>>(big1, projwT, projb, outp);
}

// Round 16
// 297.473 us; speedup vs baseline: 1.0381x; 1.0079x over previous
//
#include <hip/hip_runtime.h>
#include <math.h>

#define DEV static __device__ __forceinline__

typedef unsigned int  u32;
typedef unsigned short u16;

using bf16x8 = __attribute__((ext_vector_type(8))) __bf16;
using f32x4  = __attribute__((ext_vector_type(4))) float;

static constexpr int B_ = 16;
static constexpr int C_ = 512;
static constexpr int H_ = 48;
static constexpr int W_ = 48;
static constexpr int L_ = 2304;      // H*W
static constexpr int M_ = B_ * L_;   // 36864
static constexpr int SEG_ = 48;      // scan segments (2304 = 48*48)
static constexpr int TSEG_ = 48;
static constexpr int NLB_ = 144;     // ln_in blocks per batch (L/16)

DEV float silu_(float v) { return v / (1.f + __expf(-v)); }
DEV float bflo(u32 p) { return __uint_as_float(p << 16); }
DEV float bfhi(u32 p) { return __uint_as_float(p & 0xffff0000u); }
DEV float bf2f(u16 v) { return __uint_as_float(((u32)v) << 16); }
DEV u16 f2bf(float f) { u32 u = __float_as_uint(f); u32 r = u + 0x7fffu + ((u >> 16) & 1u); return (u16)(r >> 16); }

// direction k, segment s (TSEG=48): sp = sp0 + step*i, i in [0,48)
DEV void seg_affine(int k, int s, int& sp0, int& step) {
  if (k == 0)      { sp0 = 48 * s;        step = 1;   }
  else if (k == 1) { sp0 = 2303 - 48 * s; step = -1;  }
  else if (k == 2) { sp0 = s;             step = 48;  }
  else             { sp0 = 2303 - s;      step = -48; }
}

// ================= MFMA GEMM helpers (tiles with T2 XOR swizzle) =================
DEV void stage_tile(u16* Ls, const u16* __restrict__ g, int ld) {
  const int tid = threadIdx.x;
  #pragma unroll
  for (int i = 0; i < 4; ++i) {
    int c = i * 256 + tid;
    int row = c >> 3, slot = c & 7;
    uint4 v = *(const uint4*)(g + (size_t)row * ld + slot * 8);
    int b = row * 128 + ((slot * 16) ^ ((row & 7) << 4));
    *(uint4*)((char*)Ls + b) = v;
  }
}

DEV void stage_tile32(u16* Ls, const u16* __restrict__ g, int ld) {
  const int c = threadIdx.x;
  int row = c >> 3, slot = c & 7;
  uint4 v = *(const uint4*)(g + (size_t)row * ld + slot * 8);
  int b = row * 128 + ((slot * 16) ^ ((row & 7) << 4));
  *(uint4*)((char*)Ls + b) = v;
}

DEV bf16x8 lds_frag(const u16* Ls, int row, int kbyte) {
  int b = row * 128 + (kbyte ^ ((row & 7) << 4));
  return *(const bf16x8*)((const char*)Ls + b);
}

// ---------------- K0: weight prep ----------------
__global__ __launch_bounds__(256) void k_prep(const float* __restrict__ Win,
    const float* __restrict__ Wout, const float* __restrict__ projw,
    u16* __restrict__ WinT, u16* __restrict__ WoutT, u16* __restrict__ projwT) {
  int id = blockIdx.x * 256 + threadIdx.x;
  if (id < 131072) {
    int k = id >> 15, rem = id & 32767;
    int r = rem >> 8, n = rem & 255;
    WinT[(k << 15) + n * 128 + r] = f2bf(Win[id]);
  } else if (id < 196608) {
    int t = id - 131072;
    int k = t >> 14, rem = t & 16383;
    int r = rem >> 7, n = rem & 127;
    WoutT[(k << 14) + n * 128 + r] = f2bf(Wout[t]);
  } else {
    int t = id - 196608;
    int r = t >> 9, n = t & 511;
    projwT[n * 512 + r] = f2bf(projw[t]);
  }
}

// ---------------- K1: layernorm over C + fused SE column partials ----------------
__global__ __launch_bounds__(256) void k_ln_in(const float* __restrict__ x,
    const float* __restrict__ w, const float* __restrict__ bia, u16* __restrict__ xs,
    float* __restrict__ zpart) {
  __shared__ float tile[16 * 513];
  __shared__ float smean[16], srstd[16];
  const int b = blockIdx.y;
  const int l0 = blockIdx.x * 16;
  const int tid = threadIdx.x;
  const float* xb = x + (size_t)b * C_ * L_;
  #pragma unroll
  for (int i = 0; i < 8; ++i) {
    int idx4 = i * 256 + tid;
    int c = idx4 >> 2, lt4 = (idx4 & 3) * 4;
    float4 v = *(const float4*)(xb + (size_t)c * L_ + l0 + lt4);
    tile[(lt4 + 0) * 513 + c] = v.x;
    tile[(lt4 + 1) * 513 + c] = v.y;
    tile[(lt4 + 2) * 513 + c] = v.z;
    tile[(lt4 + 3) * 513 + c] = v.w;
  }
  __syncthreads();
  {
    const int j = tid & 15, g = tid >> 4;
    float s1 = 0.f, s2 = 0.f;
    #pragma unroll
    for (int i = 0; i < 32; ++i) {
      float v = tile[g * 513 + j + i * 16];
      s1 += v; s2 += v * v;
    }
    #pragma unroll
    for (int o = 8; o; o >>= 1) { s1 += __shfl_xor(s1, o, 16); s2 += __shfl_xor(s2, o, 16); }
    if (j == 0) {
      float mean = s1 * (1.f / C_);
      float var = s2 * (1.f / C_) - mean * mean;
      smean[g] = mean;
      srstd[g] = rsqrtf(var + 1e-5f);
    }
  }
  __syncthreads();
  float p0 = 0.f, p1 = 0.f;
  for (int idx = tid; idx < 16 * C_; idx += 256) {
    int lt = idx >> 9, c = idx & 511;
    float v = (tile[lt * 513 + c] - smean[lt]) * srstd[lt] * w[c] + bia[c];
    xs[((size_t)b * L_ + l0 + lt) * C_ + c] = f2bf(v);
    if (c == tid) p0 += v; else p1 += v;
  }
  float* zp = zpart + ((size_t)b * NLB_ + blockIdx.x) * 512;
  zp[tid] = p0;
  zp[tid + 256] = p1;
}

// ---------------- K2: SE column partial merge (6-way parallel) ----------------
__global__ __launch_bounds__(256) void k_colsum_fin(const float* __restrict__ zpart, float* __restrict__ z6) {
  const int c = blockIdx.x * 256 + threadIdx.x;
  const int b = blockIdx.y;
  const int ch = blockIdx.z;
  float acc = 0.f;
  for (int s = ch * 24; s < ch * 24 + 24; ++s) acc += zpart[((size_t)b * NLB_ + s) * 512 + c];
  z6[((size_t)b * 6 + ch) * 512 + c] = acc;
}

// ---------------- K3: SE MLP (merges 6 partials) ----------------
__global__ __launch_bounds__(256) void k_se(const float* __restrict__ z6,
    const float* __restrict__ fc1w, const float* __restrict__ fc1b,
    const float* __restrict__ fc2w, const float* __restrict__ fc2b, float* __restrict__ se) {
  __shared__ float zs[512];
  __shared__ float hs[32];
  const int b = blockIdx.x, tid = threadIdx.x;
  {
    float a0 = 0.f, a1 = 0.f;
    #pragma unroll
    for (int ch = 0; ch < 6; ++ch) {
      a0 += z6[((size_t)b * 6 + ch) * 512 + tid];
      a1 += z6[((size_t)b * 6 + ch) * 512 + tid + 256];
    }
    zs[tid] = a0 * (1.f / L_);
    zs[tid + 256] = a1 * (1.f / L_);
  }
  __syncthreads();
  if (tid < 32) {
    float a = fc1b[tid];
    for (int c = 0; c < 512; ++c) a += zs[c] * fc1w[c * 32 + tid];
    hs[tid] = fmaxf(a, 0.f);
  }
  __syncthreads();
  for (int c = tid; c < 512; c += 256) {
    float a = fc2b[c];
    #pragma unroll
    for (int r = 0; r < 32; ++r) a += hs[r] * fc2w[r * 512 + c];
    se[b * C_ + c] = 1.f / (1.f + __expf(-a));
  }
}

// ---------------- K4: xz GEMM (MFMA), XCD-chunk swizzled ----------------
__global__ __launch_bounds__(256) void k_gemm_xz(const u16* __restrict__ xs,
    const u16* __restrict__ WinT, u16* __restrict__ xin, u16* __restrict__ zbuf) {
  __shared__ u16 lds[16384];
  u16* As = lds; u16* Bs = lds + 8192;
  const int hw = blockIdx.x;
  const int lg = (hw & 7) * 288 + (hw >> 3);
  const int nb = lg & 1;
  const int m0 = ((lg >> 1) % 288) * 128;
  const int k = lg / 576;
  const int tid = threadIdx.x, l = tid & 63, w = tid >> 6;
  const int wm = w >> 1, wn = w & 1;
  const int fr = l & 15, fg = l >> 4;
  f32x4 acc[4][4];
  #pragma unroll
  for (int mi = 0; mi < 4; ++mi)
    #pragma unroll
    for (int ni = 0; ni < 4; ++ni) acc[mi][ni] = (f32x4){0.f, 0.f, 0.f, 0.f};
  const u16* Ag = xs + (size_t)m0 * 512 + k * 128;
  const u16* Bg = WinT + (size_t)k * 32768 + (size_t)nb * 16384;
  #pragma unroll
  for (int kk0 = 0; kk0 < 128; kk0 += 64) {
    stage_tile(As, Ag + kk0, 512);
    stage_tile(Bs, Bg + kk0, 128);
    __syncthreads();
    bf16x8 af[2][4], bfr[2][4];
    #pragma unroll
    for (int h = 0; h < 2; ++h)
      #pragma unroll
      for (int s = 0; s < 4; ++s) {
        af[h][s]  = lds_frag(As, wm * 64 + s * 16 + fr, h * 64 + fg * 16);
        bfr[h][s] = lds_frag(Bs, wn * 64 + s * 16 + fr, h * 64 + fg * 16);
      }
    #pragma unroll
    for (int h = 0; h < 2; ++h)
      #pragma unroll
      for (int mi = 0; mi < 4; ++mi)
        #pragma unroll
        for (int ni = 0; ni < 4; ++ni)
          acc[mi][ni] = __builtin_amdgcn_mfma_f32_16x16x32_bf16(af[h][mi], bfr[h][ni], acc[mi][ni], 0, 0, 0);
    __syncthreads();
  }
  #pragma unroll
  for (int mi = 0; mi < 4; ++mi)
    #pragma unroll
    for (int ni = 0; ni < 4; ++ni)
      #pragma unroll
      for (int j = 0; j < 4; ++j)
        lds[(wm * 64 + mi * 16 + fg * 4 + j) * 128 + wn * 64 + ni * 16 + fr] = f2bf(acc[mi][ni][j]);
  __syncthreads();
  u16* dst = (nb == 0 ? xin : zbuf) + ((size_t)k * M_ + m0) * 128;
  for (int idx = tid; idx < 128 * 16; idx += 256) {
    int row = idx >> 4, q = idx & 15;
    *(uint4*)&dst[(size_t)row * 128 + q * 8] = *(const uint4*)&lds[row * 128 + q * 8];
  }
}

// ---------------- K5a: dwconv (base path: writes xdbl rows for separate k_delta) ----------------
__global__ __launch_bounds__(256) void k_dwconv(const u16* __restrict__ xin,
    const float* __restrict__ cw, const float* __restrict__ cb, const float* __restrict__ Wx,
    u16* __restrict__ xc, float* __restrict__ xdbl, float* __restrict__ bc) {
  __shared__ float taps[9][128];
  __shared__ float wxs[10][128];
  __shared__ float part[16][16][10];
  const int kb = blockIdx.y;
  const int k = kb >> 4;
  const int tid = threadIdx.x;
  for (int i = tid; i < 1152; i += 256) {
    int dc = i / 9, t = i - dc * 9;
    taps[t][dc] = cw[((size_t)k * 128 + dc) * 9 + t];
  }
  for (int i = tid; i < 1280; i += 256) wxs[i >> 7][i & 127] = Wx[(size_t)k * 1280 + i];
  __syncthreads();
  const int sl = tid >> 4, g = tid & 15;
  const int sp = blockIdx.x * 16 + sl;
  const int h = sp / W_, w = sp % W_;
  const int dc0 = g * 8;
  float acc[8];
  {
    float4 b0 = *(const float4*)(cb + k * 128 + dc0);
    float4 b1 = *(const float4*)(cb + k * 128 + dc0 + 4);
    acc[0] = b0.x; acc[1] = b0.y; acc[2] = b0.z; acc[3] = b0.w;
    acc[4] = b1.x; acc[5] = b1.y; acc[6] = b1.z; acc[7] = b1.w;
  }
  const u16* base = xin + (size_t)kb * L_ * 128 + dc0;
  #pragma unroll
  for (int dy = -1; dy <= 1; ++dy) {
    int hh = h + dy;
    if (hh < 0 || hh >= H_) continue;
    #pragma unroll
    for (int dx = -1; dx <= 1; ++dx) {
      int ww = w + dx;
      if (ww < 0 || ww >= W_) continue;
      uint4 v = *(const uint4*)(base + (size_t)(hh * W_ + ww) * 128);
      const int t = (dy + 1) * 3 + dx + 1;
      acc[0] += taps[t][dc0 + 0] * bflo(v.x);
      acc[1] += taps[t][dc0 + 1] * bfhi(v.x);
      acc[2] += taps[t][dc0 + 2] * bflo(v.y);
      acc[3] += taps[t][dc0 + 3] * bfhi(v.y);
      acc[4] += taps[t][dc0 + 4] * bflo(v.z);
      acc[5] += taps[t][dc0 + 5] * bfhi(v.z);
      acc[6] += taps[t][dc0 + 6] * bflo(v.w);
      acc[7] += taps[t][dc0 + 7] * bfhi(v.w);
    }
  }
  float u[8];
  u16 ov[8];
  #pragma unroll
  for (int j = 0; j < 8; ++j) { u[j] = silu_(acc[j]); ov[j] = f2bf(u[j]); }
  *(uint4*)(xc + ((size_t)kb * L_ + sp) * 128 + dc0) = *(const uint4*)ov;
  #pragma unroll
  for (int r = 0; r < 10; ++r) {
    float pv = 0.f;
    #pragma unroll
    for (int j = 0; j < 8; ++j) pv += wxs[r][dc0 + j] * u[j];
    part[sl][g][r] = pv;
  }
  __syncthreads();
  if (tid < 160) {
    int sl2 = tid / 10, r = tid - sl2 * 10;
    float s = 0.f;
    #pragma unroll
    for (int g2 = 0; g2 < 16; ++g2) s += part[sl2][g2][r];
    size_t spg = (size_t)kb * L_ + blockIdx.x * 16 + sl2;
    if (r < 8) xdbl[spg * 8 + r] = s;
    else       bc[spg * 2 + (r - 8)] = s;
  }
}

// ---------------- K5b: dwconv FUSED with delta (needs separate delt buffer) ----------------
__global__ __launch_bounds__(256) void k_dwconv_f(const u16* __restrict__ xin,
    const float* __restrict__ cw, const float* __restrict__ cb, const float* __restrict__ Wx,
    const float* __restrict__ Wdt, const float* __restrict__ dtb,
    u16* __restrict__ xc, u16* __restrict__ delt, float* __restrict__ bc) {
  __shared__ float taps[9][128];
  __shared__ float wxs[10][128];
  __shared__ float part[16][16][10];
  __shared__ float xr[16][8];
  const int kb = blockIdx.y;
  const int k = kb >> 4;
  const int tid = threadIdx.x;
  for (int i = tid; i < 1152; i += 256) {
    int dc = i / 9, t = i - dc * 9;
    taps[t][dc] = cw[((size_t)k * 128 + dc) * 9 + t];
  }
  for (int i = tid; i < 1280; i += 256) wxs[i >> 7][i & 127] = Wx[(size_t)k * 1280 + i];
  const int dcq = tid & 127, shalf = tid >> 7;
  const float4 wd0 = *(const float4*)(Wdt + (size_t)k * 1024 + dcq * 8);
  const float4 wd1 = *(const float4*)(Wdt + (size_t)k * 1024 + dcq * 8 + 4);
  const float db = dtb[k * 128 + dcq];
  __syncthreads();
  const int sl = tid >> 4, g = tid & 15;
  const int sp = blockIdx.x * 16 + sl;
  const int h = sp / W_, w = sp % W_;
  const int dc0 = g * 8;
  float acc[8];
  {
    float4 b0 = *(const float4*)(cb + k * 128 + dc0);
    float4 b1 = *(const float4*)(cb + k * 128 + dc0 + 4);
    acc[0] = b0.x; acc[1] = b0.y; acc[2] = b0.z; acc[3] = b0.w;
    acc[4] = b1.x; acc[5] = b1.y; acc[6] = b1.z; acc[7] = b1.w;
  }
  const u16* base = xin + (size_t)kb * L_ * 128 + dc0;
  #pragma unroll
  for (int dy = -1; dy <= 1; ++dy) {
    int hh = h + dy;
    if (hh < 0 || hh >= H_) continue;
    #pragma unroll
    for (int dx = -1; dx <= 1; ++dx) {
      int ww = w + dx;
      if (ww < 0 || ww >= W_) continue;
      uint4 v = *(const uint4*)(base + (size_t)(hh * W_ + ww) * 128);
      const int t = (dy + 1) * 3 + dx + 1;
      acc[0] += taps[t][dc0 + 0] * bflo(v.x);
      acc[1] += taps[t][dc0 + 1] * bfhi(v.x);
      acc[2] += taps[t][dc0 + 2] * bflo(v.y);
      acc[3] += taps[t][dc0 + 3] * bfhi(v.y);
      acc[4] += taps[t][dc0 + 4] * bflo(v.z);
      acc[5] += taps[t][dc0 + 5] * bfhi(v.z);
      acc[6] += taps[t][dc0 + 6] * bflo(v.w);
      acc[7] += taps[t][dc0 + 7] * bfhi(v.w);
    }
  }
  float u[8];
  u16 ov[8];
  #pragma unroll
  for (int j = 0; j < 8; ++j) { u[j] = silu_(acc[j]); ov[j] = f2bf(u[j]); }
  *(uint4*)(xc + ((size_t)kb * L_ + sp) * 128 + dc0) = *(const uint4*)ov;
  #pragma unroll
  for (int r = 0; r < 10; ++r) {
    float pv = 0.f;
    #pragma unroll
    for (int j = 0; j < 8; ++j) pv += wxs[r][dc0 + j] * u[j];
    part[sl][g][r] = pv;
  }
  __syncthreads();
  if (tid < 160) {
    int sl2 = tid / 10, r = tid - sl2 * 10;
    float s = 0.f;
    #pragma unroll
    for (int g2 = 0; g2 < 16; ++g2) s += part[sl2][g2][r];
    if (r < 8) xr[sl2][r] = s;
    else       bc[((size_t)kb * L_ + blockIdx.x * 16 + sl2) * 2 + (r - 8)] = s;
  }
  __syncthreads();
  u16* dst = delt + ((size_t)kb * L_ + blockIdx.x * 16 + shalf * 8) * 128 + dcq;
  #pragma unroll
  for (int i = 0; i < 8; ++i) {
    const float* r = xr[shalf * 8 + i];
    float dt = db + wd0.x * r[0] + wd0.y * r[1] + wd0.z * r[2] + wd0.w * r[3]
                  + wd1.x * r[4] + wd1.y * r[5] + wd1.z * r[6] + wd1.w * r[7];
    float delta = (dt > 20.f) ? dt : __logf(1.f + __expf(dt));
    dst[(size_t)i * 128] = f2bf(delta);
  }
}

// ---------------- K6: delta (base path only) ----------------
__global__ __launch_bounds__(256) void k_delta(const float* __restrict__ xdbl,
    const float* __restrict__ Wdt, const float* __restrict__ dtb, u16* __restrict__ delt) {
  __shared__ float xrow[16][8];
  const int kb = blockIdx.y;
  const int k = kb >> 4;
  const int tid = threadIdx.x;
  const int sp0 = blockIdx.x * 16;
  if (tid < 128) {
    int sl = tid >> 3, r = tid & 7;
    xrow[sl][r] = xdbl[((size_t)kb * L_ + sp0 + sl) * 8 + r];
  }
  const int dc = tid & 127, shalf = tid >> 7;
  const float4 w0 = *(const float4*)(Wdt + (size_t)k * 1024 + dc * 8);
  const float4 w1 = *(const float4*)(Wdt + (size_t)k * 1024 + dc * 8 + 4);
  const float db = dtb[k * 128 + dc];
  __syncthreads();
  u16* dst = delt + ((size_t)kb * L_ + sp0 + shalf * 8) * 128 + dc;
  #pragma unroll
  for (int i = 0; i < 8; ++i) {
    const float* r = xrow[shalf * 8 + i];
    float dt = db + w0.x * r[0] + w0.y * r[1] + w0.z * r[2] + w0.w * r[3]
                  + w1.x * r[4] + w1.y * r[5] + w1.z * r[6] + w1.w * r[7];
    float delta = (dt > 20.f) ? dt : __logf(1.f + __expf(dt));
    dst[(size_t)i * 128] = f2bf(delta);
  }
}

// ---------------- K7: scan pass A ----------------
__global__ __launch_bounds__(256) void k_scan_passA(const u16* __restrict__ xc,
    const u16* __restrict__ delt, const float* __restrict__ bc,
    const float* __restrict__ Alog, float* __restrict__ segA, float* __restrict__ segB) {
  const int kb = blockIdx.y;
  const int k = kb >> 4;
  const int s = blockIdx.x * 2 + (threadIdx.x >> 7);
  const int dc = threadIdx.x & 127;
  const float Aa = -__expf(Alog[k * 128 + dc]);
  int sp0, step;
  seg_affine(k, s, sp0, step);
  const u16* up = xc + ((size_t)kb * L_ + sp0) * 128 + dc;
  const u16* dp = delt + ((size_t)kb * L_ + sp0) * 128 + dc;
  const float* bp = bc + ((size_t)kb * L_ + sp0) * 2;
  const int ustep = step * 128, bstep = step * 2;
  float a = 1.f, bacc = 0.f;
  #pragma unroll 4
  for (int i = 0; i < TSEG_; ++i) {
    float Bm = bp[0];
    float u = bf2f(*up);
    float delta = bf2f(*dp);
    float dA = __expf(delta * Aa);
    a *= dA;
    bacc = dA * bacc + delta * u * Bm;
    up += ustep; dp += ustep; bp += bstep;
  }
  segA[((size_t)kb * SEG_ + s) * 128 + dc] = a;
  segB[((size_t)kb * SEG_ + s) * 128 + dc] = bacc;
}

// ---------------- K8: scan pass B ----------------
__global__ __launch_bounds__(128) void k_scan_passB(const float* __restrict__ segA,
    const float* __restrict__ segB, float* __restrict__ hpre) {
  const int kb = blockIdx.x;
  const int dc = threadIdx.x;
  float h = 0.f;
  for (int s = 0; s < SEG_; ++s) {
    size_t o = ((size_t)kb * SEG_ + s) * 128 + dc;
    hpre[o] = h;
    h = segA[o] * h + segB[o];
  }
}

// ---------------- K9: scan pass C: apply + fused onorm-LN + silu gate ----------------
__global__ __launch_bounds__(256) void k_scan_passC(u16* __restrict__ xc,
    const u16* __restrict__ delt, const float* __restrict__ bc, const u16* __restrict__ zbuf,
    const float* __restrict__ Alog, const float* __restrict__ Dp, const float* __restrict__ hpre,
    const float* __restrict__ ow, const float* __restrict__ ob) {
  const int unit = blockIdx.x * 4 + (threadIdx.x >> 6);
  const int kb = unit / SEG_;
  const int s = unit - kb * SEG_;
  const int k = kb >> 4;
  const int lane = threadIdx.x & 63;
  const float Aa0 = -__expf(Alog[k * 128 + lane]);
  const float Aa1 = -__expf(Alog[k * 128 + lane + 64]);
  const float Dv0 = Dp[k * 128 + lane],      Dv1 = Dp[k * 128 + lane + 64];
  const float lw0 = ow[k * 128 + lane],      lw1 = ow[k * 128 + lane + 64];
  const float lb0 = ob[k * 128 + lane],      lb1 = ob[k * 128 + lane + 64];
  int sp0, step;
  seg_affine(k, s, sp0, step);
  size_t base = ((size_t)kb * L_ + sp0) * 128 + lane;
  u16* up = xc + base;
  const u16* dp = delt + base;
  const u16* zp = zbuf + base;
  const float* bp = bc + ((size_t)kb * L_ + sp0) * 2;
  const int ustep = step * 128, bstep = step * 2;
  float h0 = hpre[((size_t)kb * SEG_ + s) * 128 + lane];
  float h1 = hpre[((size_t)kb * SEG_ + s) * 128 + lane + 64];
  for (int i = 0; i < TSEG_; ++i) {
    float Bm = bp[0], Cm = bp[1];
    float u0 = bf2f(up[0]), u1 = bf2f(up[64]);
    float d0 = bf2f(dp[0]), d1 = bf2f(dp[64]);
    float z0 = bf2f(zp[0]), z1 = bf2f(zp[64]);
    float dA0 = __expf(d0 * Aa0), dA1 = __expf(d1 * Aa1);
    h0 = dA0 * h0 + d0 * u0 * Bm;
    h1 = dA1 * h1 + d1 * u1 * Bm;
    float y0 = h0 * Cm + Dv0 * u0;
    float y1 = h1 * Cm + Dv1 * u1;
    float s1 = y0 + y1, s2 = y0 * y0 + y1 * y1;
    #pragma unroll
    for (int o = 32; o; o >>= 1) { s1 += __shfl_xor(s1, o, 64); s2 += __shfl_xor(s2, o, 64); }
    float mean = s1 * (1.f / 128.f);
    float rstd = rsqrtf(s2 * (1.f / 128.f) - mean * mean + 1e-5f);
    up[0]  = f2bf(((y0 - mean) * rstd * lw0 + lb0) * silu_(z0));
    up[64] = f2bf(((y1 - mean) * rstd * lw1 + lb1) * silu_(z1));
    up += ustep; dp += ustep; zp += ustep; bp += bstep;
  }
}

// ---------------- K11: fused Wout GEMM (all 4 k) + skip*xh*se + row-LN(512) ----------------
__global__ __launch_bounds__(256) void k_wout_ln(const u16* __restrict__ t,
    const u16* __restrict__ WoutT, const u16* __restrict__ xs, const float* __restrict__ se,
    const float* __restrict__ skip, const float* __restrict__ nw, const float* __restrict__ nb,
    u16* __restrict__ xln) {
  __shared__ u16 As[2048];
  __shared__ u16 Bs[8192];
  __shared__ u16 stage[32 * 520];
  const int m0 = blockIdx.x * 32;
  const int tid = threadIdx.x, l = tid & 63, w = tid >> 6;
  const int wm = w >> 1, wn = w & 1;
  const int fr = l & 15, fg = l >> 4;
  for (int k = 0; k < 4; ++k) {
    f32x4 acc[4];
    #pragma unroll
    for (int ni = 0; ni < 4; ++ni) acc[ni] = (f32x4){0.f, 0.f, 0.f, 0.f};
    const u16* Ag = t + ((size_t)k * M_ + m0) * 128;
    const u16* Bg = WoutT + (size_t)k * 16384;
    #pragma unroll
    for (int kk0 = 0; kk0 < 128; kk0 += 64) {
      stage_tile32(As, Ag + kk0, 128);
      stage_tile(Bs, Bg + kk0, 128);
      __syncthreads();
      bf16x8 af[2], bfr[2][4];
      #pragma unroll
      for (int h = 0; h < 2; ++h) {
        af[h] = lds_frag(As, wm * 16 + fr, h * 64 + fg * 16);
        #pragma unroll
        for (int s = 0; s < 4; ++s)
          bfr[h][s] = lds_frag(Bs, wn * 64 + s * 16 + fr, h * 64 + fg * 16);
      }
      #pragma unroll
      for (int h = 0; h < 2; ++h)
        #pragma unroll
        for (int ni = 0; ni < 4; ++ni)
          acc[ni] = __builtin_amdgcn_mfma_f32_16x16x32_bf16(af[h], bfr[h][ni], acc[ni], 0, 0, 0);
      __syncthreads();
    }
    #pragma unroll
    for (int ni = 0; ni < 4; ++ni)
      #pragma unroll
      for (int j = 0; j < 4; ++j)
        stage[(wm * 16 + fg * 4 + j) * 520 + k * 128 + wn * 64 + ni * 16 + fr] = f2bf(acc[ni][j]);
  }
  __syncthreads();
  const int row = tid >> 3, t7 = tid & 7;
  const int m = m0 + row;
  const int b = m / L_;
  const float sk = skip[0];
  float s1 = 0.f, s2 = 0.f;
  #pragma unroll
  for (int i = 0; i < 8; ++i) {
    int col = t7 * 8 + i * 64;
    uint4 cv = *(const uint4*)&stage[row * 520 + col];
    uint4 xv = *(const uint4*)&xs[(size_t)m * 512 + col];
    float4 e0 = *(const float4*)&se[b * 512 + col];
    float4 e1 = *(const float4*)&se[b * 512 + col + 4];
    float o[8];
    o[0] = bflo(cv.x) * sk * bflo(xv.x) * e0.x;
    o[1] = bfhi(cv.x) * sk * bfhi(xv.x) * e0.y;
    o[2] = bflo(cv.y) * sk * bflo(xv.y) * e0.z;
    o[3] = bfhi(cv.y) * sk * bfhi(xv.y) * e0.w;
    o[4] = bflo(cv.z) * sk * bflo(xv.z) * e1.x;
    o[5] = bfhi(cv.z) * sk * bfhi(xv.z) * e1.y;
    o[6] = bflo(cv.w) * sk * bflo(xv.w) * e1.z;
    o[7] = bfhi(cv.w) * sk * bfhi(xv.w) * e1.w;
    u16 ov[8];
    #pragma unroll
    for (int j = 0; j < 8; ++j) { s1 += o[j]; s2 += o[j] * o[j]; ov[j] = f2bf(o[j]); }
    *(uint4*)&stage[row * 520 + col] = *(const uint4*)ov;
  }
  #pragma unroll
  for (int o = 4; o; o >>= 1) { s1 += __shfl_xor(s1, o, 64); s2 += __shfl_xor(s2, o, 64); }
  float mean = s1 * (1.f / C_);
  float rstd = rsqrtf(s2 * (1.f / C_) - mean * mean + 1e-5f);
  #pragma unroll
  for (int i = 0; i < 8; ++i) {
    int col = t7 * 8 + i * 64;
    uint4 cv = *(const uint4*)&stage[row * 520 + col];
    float4 w0 = *(const float4*)&nw[col];
    float4 w1 = *(const float4*)&nw[col + 4];
    float4 b0 = *(const float4*)&nb[col];
    float4 b1 = *(const float4*)&nb[col + 4];
    u16 ov[8];
    ov[0] = f2bf((bflo(cv.x) - mean) * rstd * w0.x + b0.x);
    ov[1] = f2bf((bfhi(cv.x) - mean) * rstd * w0.y + b0.y);
    ov[2] = f2bf((bflo(cv.y) - mean) * rstd * w0.z + b0.z);
    ov[3] = f2bf((bfhi(cv.y) - mean) * rstd * w0.w + b0.w);
    ov[4] = f2bf((bflo(cv.z) - mean) * rstd * w1.x + b1.x);
    ov[5] = f2bf((bfhi(cv.z) - mean) * rstd * w1.y + b1.y);
    ov[6] = f2bf((bflo(cv.w) - mean) * rstd * w1.z + b1.z);
    ov[7] = f2bf((bfhi(cv.w) - mean) * rstd * w1.w + b1.w);
    *(uint4*)&xln[(size_t)m * 512 + col] = *(const uint4*)ov;
  }
}

// ---------------- K13: proj GEMM (MFMA) + bias, XCD-chunk swizzled, transposed write ----------------
__global__ __launch_bounds__(256) void k_gemm_proj(const u16* __restrict__ xln,
    const u16* __restrict__ projwT, const float* __restrict__ projb, float* __restrict__ outp) {
  __shared__ float ldsp[8448];
  u16* As = (u16*)ldsp; u16* Bs = As + 8192;
  const int hw = blockIdx.x;
  const int lg = (hw & 7) * 144 + (hw >> 3);
  const int n0 = (lg & 3) * 128;
  const int m0 = (lg >> 2) * 128;
  const int tid = threadIdx.x, l = tid & 63, w = tid >> 6;
  const int wm = w >> 1, wn = w & 1;
  const int fr = l & 15, fg = l >> 4;
  f32x4 acc[4][4];
  #pragma unroll
  for (int mi = 0; mi < 4; ++mi)
    #pragma unroll
    for (int ni = 0; ni < 4; ++ni) acc[mi][ni] = (f32x4){0.f, 0.f, 0.f, 0.f};
  const u16* Ag = xln + (size_t)m0 * 512;
  const u16* Bg = projwT + (size_t)n0 * 512;
  for (int kk0 = 0; kk0 < 512; kk0 += 64) {
    stage_tile(As, Ag + kk0, 512);
    stage_tile(Bs, Bg + kk0, 512);
    __syncthreads();
    bf16x8 af[2][4], bfr[2][4];
    #pragma unroll
    for (int h = 0; h < 2; ++h)
      #pragma unroll
      for (int s = 0; s < 4; ++s) {
        af[h][s]  = lds_frag(As, wm * 64 + s * 16 + fr, h * 64 + fg * 16);
        bfr[h][s] = lds_frag(Bs, wn * 64 + s * 16 + fr, h * 64 + fg * 16);
      }
    #pragma unroll
    for (int h = 0; h < 2; ++h)
      #pragma unroll
      for (int mi = 0; mi < 4; ++mi)
        #pragma unroll
        for (int ni = 0; ni < 4; ++ni)
          acc[mi][ni] = __builtin_amdgcn_mfma_f32_16x16x32_bf16(af[h][mi], bfr[h][ni], acc[mi][ni], 0, 0, 0);
    __syncthreads();
  }
  const int b = m0 / L_, sp0 = m0 % L_;
  #pragma unroll
  for (int half = 0; half < 2; ++half) {
    if (wn == half) {
      #pragma unroll
      for (int ni = 0; ni < 4; ++ni) {
        int nl = ni * 16 + fr;
        float bias = projb[n0 + half * 64 + nl];
        #pragma unroll
        for (int mi = 0; mi < 4; ++mi)
          #pragma unroll
          for (int j = 0; j < 4; ++j)
            ldsp[nl * 132 + wm * 64 + mi * 16 + fg * 4 + j] = acc[mi][ni][j] + bias;
      }
    }
    __syncthreads();
    for (int idx = tid; idx < 64 * 32; idx += 256) {
      int n = idx >> 5, mq = idx & 31;
      float4 v = *(const float4*)&ldsp[n * 132 + mq * 4];
      *(float4*)&outp[((size_t)b * 512 + n0 + half * 64 + n) * L_ + sp0 + mq * 4] = v;
    }
    __syncthreads();
  }
}

extern "C" void kernel_launch(void* const* d_in, const int* in_sizes, int n_in,
                              void* d_out, int out_size, void* d_ws, size_t ws_size,
                              hipStream_t stream) {
  const float* x     = (const float*)d_in[0];
  const float* nw    = (const float*)d_in[1];
  const float* nb    = (const float*)d_in[2];
  const float* fc1w  = (const float*)d_in[3];
  const float* fc1b  = (const float*)d_in[4];
  const float* fc2w  = (const float*)d_in[5];
  const float* fc2b  = (const float*)d_in[6];
  const float* Win   = (const float*)d_in[7];
  const float* convw = (const float*)d_in[8];
  const float* convb = (const float*)d_in[9];
  const float* Wx    = (const float*)d_in[10];
  const float* Wdt   = (const float*)d_in[11];
  const float* dtb   = (const float*)d_in[12];
  const float* Alog  = (const float*)d_in[13];
  const float* Dp    = (const float*)d_in[14];
  const float* onw   = (const float*)d_in[15];
  const float* onb   = (const float*)d_in[16];
  const float* Wout  = (const float*)d_in[17];
  const float* projw = (const float*)d_in[18];
  const float* projb = (const float*)d_in[19];
  const float* skip  = (const float*)d_in[20];
  float* outp = (float*)d_out;

  const size_t BIGE = (size_t)4 * B_ * L_ * 128;   // 18,874,368 elements
  char* p = (char*)d_ws;
  auto carve = [&](size_t bytes) { char* r = p; p += (bytes + 255) & ~(size_t)255; return r; };
  u16*   xs     = (u16*)  carve(BIGE * 2);          // (B,L,C) bf16
  u16*   big1   = (u16*)  carve(BIGE * 2);          // xin -> (delt base path) -> xln
  u16*   big2   = (u16*)  carve(BIGE * 2);          // zbuf
  u16*   big3   = (u16*)  carve(BIGE * 2);          // xc -> t (in place)
  float* xdbl   = (float*)carve((size_t)1179648 * 4);
  float* bc     = (float*)carve((size_t)294912 * 4);
  float* segA   = (float*)carve((size_t)393216 * 4);
  float* segB   = (float*)carve((size_t)393216 * 4);
  float* hpre   = (float*)carve((size_t)393216 * 4);
  float* zpart  = (float*)carve((size_t)B_ * NLB_ * 512 * 4);
  float* z6     = (float*)carve((size_t)B_ * 6 * 512 * 4);
  float* se     = (float*)carve((size_t)8192 * 4);
  u16*   WinT   = (u16*)  carve((size_t)131072 * 2);
  u16*   WoutT  = (u16*)  carve((size_t)65536 * 2);
  u16*   projwT = (u16*)  carve((size_t)262144 * 2);
  u16*   deltf  = (u16*)  carve(BIGE * 2);          // fused-path delta buffer
  const bool fused = (size_t)(p - (char*)d_ws) <= ws_size;

  k_prep<<<1792, 256, 0, stream>>>(Win, Wout, projw, WinT, WoutT, projwT);
  k_ln_in<<<dim3(NLB_, B_), 256, 0, stream>>>(x, nw, nb, xs, zpart);
  k_colsum_fin<<<dim3(2, B_, 6), 256, 0, stream>>>(zpart, z6);
  k_se<<<B_, 256, 0, stream>>>(z6, fc1w, fc1b, fc2w, fc2b, se);
  k_gemm_xz<<<2304, 256, 0, stream>>>(xs, WinT, big1, big2);
  const u16* delt;
  if (fused) {
    k_dwconv_f<<<dim3(L_ / 16, 64), 256, 0, stream>>>(big1, convw, convb, Wx, Wdt, dtb, big3, deltf, bc);
    delt = deltf;
  } else {
    k_dwconv<<<dim3(L_ / 16, 64), 256, 0, stream>>>(big1, convw, convb, Wx, big3, xdbl, bc);
    k_delta<<<dim3(L_ / 16, 64), 256, 0, stream>>>(xdbl, Wdt, dtb, big1);
    delt = big1;
  }
  k_scan_passA<<<dim3(SEG_ / 2, 64), 256, 0, stream>>>(big3, delt, bc, Alog, segA, segB);
  k_scan_passB<<<64, 128, 0, stream>>>(segA, segB, hpre);
  k_scan_passC<<<SEG_ * 64 / 4, 256, 0, stream>>>(big3, delt, bc, big2, Alog, Dp, hpre, onw, onb);
  k_wout_ln<<<M_ / 32, 256, 0, stream>>>(big3, WoutT, xs, se, skip, nw, nb, big1);
  k_gemm_proj<<<1152, 256, 0, stream>>>(big1, projwT, projb, outp);
}